// Round 10
// baseline (84.570 us; speedup 1.0000x reference)
//
#include <hip/hip_runtime.h>
#include <math.h>

#define NQ 10
typedef float v2f __attribute__((ext_vector_type(2)));

#if defined(__has_builtin)
#if __has_builtin(__builtin_amdgcn_permlane16_swap) && __has_builtin(__builtin_amdgcn_permlane32_swap)
#define HAVE_PL 1
#endif
#endif

template<int CTRL>
__device__ __forceinline__ float dppf(float x) {
    return __int_as_float(__builtin_amdgcn_update_dpp(
        __float_as_int(x), __float_as_int(x), CTRL, 0xF, 0xF, true));
}
template<int OFS>
__device__ __forceinline__ float swzf(float x) {
    return __int_as_float(__builtin_amdgcn_ds_swizzle(__float_as_int(x), OFS));
}
__device__ __forceinline__ float bperm(int idx, float x) {
    return __int_as_float(__builtin_amdgcn_ds_bpermute(idx, __float_as_int(x)));
}

// partner on lane-bit P for P=0..3 — ALL VALU DPP now:
//   xor1 = quad_perm[1,0,3,2] (0xB1); xor2 = quad_perm[2,3,0,1] (0x4E);
//   xor4 = row_half_mirror (xor7, 0x141) then quad_perm[3,2,1,0] (xor3, 0x1B);
//   xor8 = row_ror:8 (0x128).
template<int P>
__device__ __forceinline__ float partner1(float x) {
    if constexpr (P == 0) return dppf<0xB1>(x);
    else if constexpr (P == 1) return dppf<0x4E>(x);
    else if constexpr (P == 2) return dppf<0x1B>(dppf<0x141>(x));
    else return dppf<0x128>(x);
}
template<int P>
__device__ __forceinline__ v2f partner2(v2f v) {
    v2f r; r.x = partner1<P>(v.x); r.y = partner1<P>(v.y); return r;
}

// block swap on lane-bit P (P=4 or 5): returns {v0, v1} = pair members with bit P = 0 / 1
// CDNA4 V_PERMLANE16_SWAP_B32 with DST=SRC=x: result[0]=x[i&~16] (V0), result[1]=x[i|16] (V1).
// V_PERMLANE32_SWAP_B32: result[0]=x[i&~32] (V0), result[1]=x[i|32] (V1).
struct FPair { float v0, v1; };
template<int P>
__device__ __forceinline__ FPair blkswap1(float x, int lane) {
    FPair o;
#ifdef HAVE_PL
    if constexpr (P == 4) {
        auto r = __builtin_amdgcn_permlane16_swap(__float_as_uint(x), __float_as_uint(x), false, false);
        o.v0 = __uint_as_float(r[0]);
        o.v1 = __uint_as_float(r[1]);
    } else {
        auto r = __builtin_amdgcn_permlane32_swap(__float_as_uint(x), __float_as_uint(x), false, false);
        o.v0 = __uint_as_float(r[0]);
        o.v1 = __uint_as_float(r[1]);
    }
#else
    const float p = (P == 4) ? swzf<0x401F>(x) : bperm((lane ^ 32) << 2, x);
    const bool hi = (lane >> P) & 1;
    o.v0 = hi ? p : x;
    o.v1 = hi ? x : p;
#endif
    return o;
}
struct VPair { v2f V0, V1; };
template<int P>
__device__ __forceinline__ VPair blkswap2(v2f x, int lane) {
    const FPair a = blkswap1<P>(x.x, lane);
    const FPair b = blkswap1<P>(x.y, lane);
    VPair o;
    o.V0 = (v2f){a.v0, b.v0};
    o.V1 = (v2f){a.v1, b.v1};
    return o;
}
template<int P>
__device__ __forceinline__ float blkadd(float x, int lane) {
    const FPair o = blkswap1<P>(x, lane);
    return o.v0 + o.v1;
}

// ---- gate bodies ----
template<int P>
__device__ __forceinline__ void gate_blk_full(v2f (&Sr)[8], v2f (&Si)[8], int lane,
                                              float er, float ei, float fr, float fi) {
#pragma unroll
    for (int k = 0; k < 8; ++k) {
        const VPair R = blkswap2<P>(Sr[k], lane);
        const VPair I = blkswap2<P>(Si[k], lane);
        Sr[k] = er * R.V0 - ei * I.V0 + fr * R.V1 - fi * I.V1;
        Si[k] = er * I.V0 + ei * R.V0 + fr * I.V1 + fi * R.V1;
    }
}
template<int P>
__device__ __forceinline__ void gate_blk_real(v2f (&Sr)[8], v2f (&Si)[8], int lane,
                                              float e, float f) {
#pragma unroll
    for (int k = 0; k < 8; ++k) {
        const VPair R = blkswap2<P>(Sr[k], lane);
        const VPair I = blkswap2<P>(Si[k], lane);
        Sr[k] = e * R.V0 + f * R.V1;
        Si[k] = e * I.V0 + f * I.V1;
    }
}
template<int P>
__device__ __forceinline__ void gate_dpp_full(v2f (&Sr)[8], v2f (&Si)[8],
                                              float dr, float di, float orr, float oii) {
#pragma unroll
    for (int k = 0; k < 8; ++k) {
        const v2f mr = Sr[k], mi = Si[k];
        const v2f pr = partner2<P>(mr);
        const v2f pi = partner2<P>(mi);
        Sr[k] = dr * mr - di * mi + orr * pr - oii * pi;
        Si[k] = dr * mi + di * mr + orr * pi + oii * pr;
    }
}
template<int P>
__device__ __forceinline__ void gate_dpp_real(v2f (&Sr)[8], v2f (&Si)[8],
                                              float cl, float sgn) {
#pragma unroll
    for (int k = 0; k < 8; ++k) {
        const v2f pr = partner2<P>(Sr[k]);
        const v2f pi = partner2<P>(Si[k]);
        Sr[k] = cl * Sr[k] + sgn * pr;
        Si[k] = cl * Si[k] + sgn * pi;
    }
}
__device__ __forceinline__ void u3_pair(v2f& a0r, v2f& a0i, v2f& a1r, v2f& a1i,
                                        float u00r, float u00i, float u01r, float u01i,
                                        float u10r, float u10i, float u11r, float u11i) {
    v2f n0r = u00r * a0r - u00i * a0i + u01r * a1r - u01i * a1i;
    v2f n0i = u00r * a0i + u00i * a0r + u01r * a1i + u01i * a1r;
    v2f n1r = u10r * a0r - u10i * a0i + u11r * a1r - u11i * a1i;
    v2f n1i = u10r * a0i + u10i * a0r + u11r * a1i + u11i * a1r;
    a0r = n0r; a0i = n0i; a1r = n1r; a1i = n1i;
}
__device__ __forceinline__ void ry_pair(v2f& a0r, v2f& a0i, v2f& a1r, v2f& a1i,
                                        float c, float s) {
    v2f n0r = c * a0r - s * a1r;
    v2f n0i = c * a0i - s * a1i;
    v2f n1r = s * a0r + c * a1r;
    v2f n1i = s * a0i + c * a1i;
    a0r = n0r; a0i = n0i; a1r = n1r; a1i = n1i;
}
__device__ __forceinline__ void cmul(float& xr, float& xi, float br, float bi) {
    const float nr = xr * br - xi * bi;
    const float ni = xr * bi + xi * br;
    xr = nr; xi = ni;
}

// scalar plus-reduction over lane bits FROM..5 (all-VALU except bits 4/5 permlane swaps)
template<int FROM>
__device__ __forceinline__ float plus_reduce(float x, int lane) {
    if constexpr (FROM <= 0) x += partner1<0>(x);
    if constexpr (FROM <= 1) x += partner1<1>(x);
    if constexpr (FROM <= 2) x += partner1<2>(x);
    if constexpr (FROM <= 3) x += partner1<3>(x);
    if constexpr (FROM <= 4) x = blkadd<4>(x, lane);
    x = blkadd<5>(x, lane);
    return x;
}
// packed v2f plus-reduction over all 6 lane bits
__device__ __forceinline__ v2f vplus_reduce(v2f x, int lane) {
    x += partner2<0>(x);
    x += partner2<1>(x);
    x += partner2<2>(x);
    x += partner2<3>(x);
    { const VPair o = blkswap2<4>(x, lane); x = o.V0 + o.V1; }
    { const VPair o = blkswap2<5>(x, lane); x = o.V0 + o.V1; }
    return x;
}

#define LOADM(P, base) \
    const float4 P##va = *(const float4*)&cs[(base)]; \
    const float4 P##vb = *(const float4*)&cs[(base) + 4]; \
    const float P##00r = P##va.x, P##00i = P##va.y, P##01r = P##va.z, P##01i = P##va.w, \
                P##10r = P##vb.x, P##10i = P##vb.y, P##11r = P##vb.z, P##11i = P##vb.w;

// Per-wave coefficient slice (cs[]) float layout:
//  [0..79]    U3_0 rows as float2 by (q, j): (q*4+j)*2 ; j: 0=(00r,01r) 1=(00i,01i) 2=(10r,11r) 3=(10i,11i)
//  [80..97]   CRY_0 e=0..8: (c,s) at 80+2e
//  [98..99]   CRY_1 e=9: (c,s)
//  [100..179] A_q = U3_1(q), 8 floats at 100+8q
//  [180..259] B_q: q=0: A_0*RY(w39); q>=1: RY(w[70+q-1])*A_q ; at 180+8q

// State layout per wave (one batch element per wave):
//   global index i[9:0], qubit q at bit p = 9-q.
//   lane = i[5:0] (qubits 4..9 on lane bits 5..0), k = i[8:6] (qubits 3,2,1 on k bits 0,1,2),
//   v2f component j = i[9] (qubit 0).
__global__ __launch_bounds__(256) void qsim(const float* __restrict__ in,
                                            const float* __restrict__ w,
                                            float* __restrict__ out, int B) {
    __shared__ __attribute__((aligned(16))) float csh[4 * 272];
    __shared__ __attribute__((aligned(16))) float tsh[4 * 40];
    const int lane = threadIdx.x & 63;
    const int wave = threadIdx.x >> 6;
    int b = blockIdx.x * 4 + wave;
    b = __builtin_amdgcn_readfirstlane(b);
    if (b >= B) return;
    float* cs = csh + wave * 272;

    // ===== per-wave distributed coefficient generation =====
    {
        const int q = (lane < 20) ? (lane % 10) : ((lane >= 40 && lane < 50) ? lane - 40 : 0);
        const int wb = (lane < 10) ? 3 * lane : 40 + 3 * q;
        const float phi = w[wb], theta = w[wb + 1], omega = w[wb + 2];
        float u0, u1, u2, u3, u4, u5, u6, u7;
        {
            const float ct = __cosf(0.5f * theta), st = __sinf(0.5f * theta);
            const float apo = 0.5f * (phi + omega), amo = 0.5f * (phi - omega);
            const float capo = __cosf(apo), sapo = __sinf(apo);
            const float camo = __cosf(amo), samo = __sinf(amo);
            u0 =  capo * ct;  u1 = -sapo * ct;   // U00
            u2 = -camo * st;  u3 = -samo * st;   // U01
            u4 =  camo * st;  u5 = -samo * st;   // U10
            u6 =  capo * ct;  u7 =  sapo * ct;   // U11
        }
        const int cidx = (lane >= 20 && lane < 29) ? 30 + (lane - 20)
                       : (lane == 29) ? 79
                       : (lane == 40) ? 39
                       : 70 + (q - 1) + (q == 0 ? 1 : 0);
        const float th = 0.5f * w[cidx];
        const float c2 = __cosf(th), s2 = __sinf(th);
        if (lane >= 40 && lane < 50) {
            const bool r = (lane == 40);       // B_0 = A*RY (right); else B_q = RY*A (left)
            const float p0 = r ? (u0 * c2 + u2 * s2) : (c2 * u0 - s2 * u4);
            const float p1 = r ? (u1 * c2 + u3 * s2) : (c2 * u1 - s2 * u5);
            const float p2 = r ? (u2 * c2 - u0 * s2) : (c2 * u2 - s2 * u6);
            const float p3 = r ? (u3 * c2 - u1 * s2) : (c2 * u3 - s2 * u7);
            const float p4 = r ? (u4 * c2 + u6 * s2) : (s2 * u0 + c2 * u4);
            const float p5 = r ? (u5 * c2 + u7 * s2) : (s2 * u1 + c2 * u5);
            const float p6 = r ? (u6 * c2 - u4 * s2) : (s2 * u2 + c2 * u6);
            const float p7 = r ? (u7 * c2 - u5 * s2) : (s2 * u3 + c2 * u7);
            u0 = p0; u1 = p1; u2 = p2; u3 = p3; u4 = p4; u5 = p5; u6 = p6; u7 = p7;
        }
        if (lane < 10) {                       // U3_0 row format
            *(float4*)&cs[lane * 8]     = (float4){u0, u2, u1, u3};
            *(float4*)&cs[lane * 8 + 4] = (float4){u4, u6, u5, u7};
        } else if (lane < 20) {                // A_q
            *(float4*)&cs[100 + (lane - 10) * 8]     = (float4){u0, u1, u2, u3};
            *(float4*)&cs[100 + (lane - 10) * 8 + 4] = (float4){u4, u5, u6, u7};
        } else if (lane < 30) {                // CRY pairs
            const int off = (lane < 29) ? 80 + 2 * (lane - 20) : 98;
            *(float2*)&cs[off] = (float2){c2, s2};
        } else if (lane >= 40 && lane < 50) {  // B_q
            *(float4*)&cs[180 + q * 8]     = (float4){u0, u1, u2, u3};
            *(float4*)&cs[180 + q * 8 + 4] = (float4){u4, u5, u6, u7};
        }
    }

    // ---- distributed input fold: lane = q*4 + j computes t-component j of qubit q ----
    if (lane < 40) {
        const int q = lane >> 2;
        float x = in[b * NQ + q];
        x = fminf(fmaxf(x, 0.0f), 1.0f);
        const float a = 0.5f * 3.14159265358979323846f * x;
        const float ca = __cosf(a), sa = __sinf(a);
        const float M0 = cs[lane * 2], M1 = cs[lane * 2 + 1];
        tsh[wave * 40 + lane] = M0 * ca + M1 * sa;
    }
    const int base = wave * 40;

    // lane-bit amplitude chain (qubit 9-j on lane bit j), complex
    float wr, wi;
    {
        const int bit = lane & 1;
        const float2 v = *(const float2*)&tsh[base + 9 * 4 + (bit << 1)];
        wr = v.x; wi = v.y;
    }
#pragma unroll
    for (int j = 1; j < 6; ++j) {
        const int bit = (lane >> j) & 1;
        const float2 v = *(const float2*)&tsh[base + (9 - j) * 4 + (bit << 1)];
        cmul(wr, wi, v.x, v.y);
    }
    const float4 T0 = *(const float4*)&tsh[base + 0];
    const float4 T1 = *(const float4*)&tsh[base + 4];
    const float4 T2 = *(const float4*)&tsh[base + 8];
    const float4 T3 = *(const float4*)&tsh[base + 12];

    float vr[4], vi[4];
    { float r = T1.x, i2 = T1.y; vr[0] = r * T2.x - i2 * T2.y; vi[0] = r * T2.y + i2 * T2.x;
                                  vr[1] = r * T2.z - i2 * T2.w; vi[1] = r * T2.w + i2 * T2.z; }
    { float r = T1.z, i2 = T1.w; vr[2] = r * T2.x - i2 * T2.y; vi[2] = r * T2.y + i2 * T2.x;
                                  vr[3] = r * T2.z - i2 * T2.w; vi[3] = r * T2.w + i2 * T2.z; }
    v2f Sr[8], Si[8];
    const v2f T0r = {T0.x, T0.z};
    const v2f T0i = {T0.y, T0.w};
#pragma unroll
    for (int k = 0; k < 8; ++k) {
        const int hv = k >> 1;
        const float t3r = (k & 1) ? T3.z : T3.x;
        const float t3i = (k & 1) ? T3.w : T3.y;
        float kr = vr[hv] * t3r - vi[hv] * t3i;
        float ki = vr[hv] * t3i + vi[hv] * t3r;
        cmul(kr, ki, wr, wi);
        Sr[k] = kr * T0r - ki * T0i;
        Si[k] = kr * T0i + ki * T0r;
    }

    // ===== CRY_0 ring, e = 0..8 =====
    {   // e0: ctrl q0 (comp), tgt q1 (k bit2)
        const float2 C = *(const float2*)&cs[80];
        const v2f cv = {1.0f, C.x};
        const v2f sv = {0.0f, C.y};
#pragma unroll
        for (int k0 = 0; k0 < 4; ++k0) {
            const int k1 = k0 | 4;
            v2f n0r = cv * Sr[k0] - sv * Sr[k1];
            v2f n0i = cv * Si[k0] - sv * Si[k1];
            v2f n1r = sv * Sr[k0] + cv * Sr[k1];
            v2f n1i = sv * Si[k0] + cv * Si[k1];
            Sr[k0] = n0r; Si[k0] = n0i; Sr[k1] = n1r; Si[k1] = n1i;
        }
    }
    {   // e1: ctrl q1 (k bit2), tgt q2 (k bit1)
        const float2 C = *(const float2*)&cs[82];
        ry_pair(Sr[4], Si[4], Sr[6], Si[6], C.x, C.y);
        ry_pair(Sr[5], Si[5], Sr[7], Si[7], C.x, C.y);
    }
    {   // e2: ctrl q2 (k bit1), tgt q3 (k bit0)
        const float2 C = *(const float2*)&cs[84];
        ry_pair(Sr[2], Si[2], Sr[3], Si[3], C.x, C.y);
        ry_pair(Sr[6], Si[6], Sr[7], Si[7], C.x, C.y);
    }
    {   // e3: ctrl q3 (k bit0) -> odd k only; tgt q4 (lane bit5), block form
        const float2 C = *(const float2*)&cs[86];
        const bool hi = (lane >> 5) & 1;
        const float e = hi ? C.y : C.x;
        const float f = hi ? C.x : -C.y;
#pragma unroll
        for (int k = 1; k < 8; k += 2) {
            const VPair R = blkswap2<5>(Sr[k], lane);
            const VPair I = blkswap2<5>(Si[k], lane);
            Sr[k] = e * R.V0 + f * R.V1;
            Si[k] = e * I.V0 + f * I.V1;
        }
    }
    {   // e4: ctrl q4 (lane bit5), tgt q5 (lane bit4), block form
        const float2 C = *(const float2*)&cs[88];
        const bool ctrl = (lane >> 5) & 1;
        const bool hi = (lane >> 4) & 1;
        const float e = ctrl ? (hi ? C.y : C.x) : (hi ? 0.0f : 1.0f);
        const float f = ctrl ? (hi ? C.x : -C.y) : (hi ? 1.0f : 0.0f);
        gate_blk_real<4>(Sr, Si, lane, e, f);
    }
    {   // e5: ctrl lane bit4, tgt lane bit3 (DPP)
        const float2 C = *(const float2*)&cs[90];
        const bool ctrl = (lane >> 4) & 1;
        const float cl = ctrl ? C.x : 1.0f;
        const float sl = ctrl ? C.y : 0.0f;
        const float sgn = ((lane >> 3) & 1) ? sl : -sl;
        gate_dpp_real<3>(Sr, Si, cl, sgn);
    }
    {   // e6: ctrl lane bit3, tgt lane bit2 (2-DPP xor4)
        const float2 C = *(const float2*)&cs[92];
        const bool ctrl = (lane >> 3) & 1;
        const float cl = ctrl ? C.x : 1.0f;
        const float sl = ctrl ? C.y : 0.0f;
        const float sgn = ((lane >> 2) & 1) ? sl : -sl;
        gate_dpp_real<2>(Sr, Si, cl, sgn);
    }
    {   // e7: ctrl lane bit2, tgt lane bit1 (DPP)
        const float2 C = *(const float2*)&cs[94];
        const bool ctrl = (lane >> 2) & 1;
        const float cl = ctrl ? C.x : 1.0f;
        const float sl = ctrl ? C.y : 0.0f;
        const float sgn = ((lane >> 1) & 1) ? sl : -sl;
        gate_dpp_real<1>(Sr, Si, cl, sgn);
    }
    {   // e8: ctrl lane bit1, tgt lane bit0 (DPP)
        const float2 C = *(const float2*)&cs[96];
        const bool ctrl = (lane >> 1) & 1;
        const float cl = ctrl ? C.x : 1.0f;
        const float sl = ctrl ? C.y : 0.0f;
        const float sgn = (lane & 1) ? sl : -sl;
        gate_dpp_real<0>(Sr, Si, cl, sgn);
    }

    // ===== F0 = U3_1(0) * CRY_0(9): ctrl q9 (lane bit0), tgt q0 (comp) =====
    {
        LOADM(A, 100); LOADM(Bm, 180);
        const bool ctrl = lane & 1;
        const float M00r = ctrl ? Bm00r : A00r, M00i = ctrl ? Bm00i : A00i;
        const float M01r = ctrl ? Bm01r : A01r, M01i = ctrl ? Bm01i : A01i;
        const float M10r = ctrl ? Bm10r : A10r, M10i = ctrl ? Bm10i : A10i;
        const float M11r = ctrl ? Bm11r : A11r, M11i = ctrl ? Bm11i : A11i;
        const v2f Dr = {M00r, M11r}, Di = {M00i, M11i};
        const v2f Or = {M01r, M10r}, Oi = {M01i, M10i};
#pragma unroll
        for (int k = 0; k < 8; ++k) {
            const v2f Ar = Sr[k], Ai = Si[k];
            const v2f Br = Ar.yx, Bi = Ai.yx;
            Sr[k] = Dr * Ar - Di * Ai + Or * Br - Oi * Bi;
            Si[k] = Dr * Ai + Di * Ar + Or * Bi + Oi * Br;
        }
    }
    // ===== F1 = CRY_1(0) * U3_1(1): ctrl q0 (comp), tgt q1 (k bit2) =====
    {
        LOADM(A, 108); LOADM(Bm, 188);
        const v2f u00r = {A00r, Bm00r}, u00i = {A00i, Bm00i};
        const v2f u01r = {A01r, Bm01r}, u01i = {A01i, Bm01i};
        const v2f u10r = {A10r, Bm10r}, u10i = {A10i, Bm10i};
        const v2f u11r = {A11r, Bm11r}, u11i = {A11i, Bm11i};
#pragma unroll
        for (int k0 = 0; k0 < 4; ++k0) {
            const int k1 = k0 | 4;
            v2f n0r = u00r * Sr[k0] - u00i * Si[k0] + u01r * Sr[k1] - u01i * Si[k1];
            v2f n0i = u00r * Si[k0] + u00i * Sr[k0] + u01r * Si[k1] + u01i * Sr[k1];
            v2f n1r = u10r * Sr[k0] - u10i * Si[k0] + u11r * Sr[k1] - u11i * Si[k1];
            v2f n1i = u10r * Si[k0] + u10i * Sr[k0] + u11r * Si[k1] + u11i * Sr[k1];
            Sr[k0] = n0r; Si[k0] = n0i; Sr[k1] = n1r; Si[k1] = n1i;
        }
    }
    // ===== F2 = CRY_1(1) * U3_1(2): ctrl q1 (k bit2), tgt q2 (k bit1) =====
    {
        LOADM(A, 116); LOADM(Bm, 196);
        u3_pair(Sr[0], Si[0], Sr[2], Si[2], A00r, A00i, A01r, A01i, A10r, A10i, A11r, A11i);
        u3_pair(Sr[1], Si[1], Sr[3], Si[3], A00r, A00i, A01r, A01i, A10r, A10i, A11r, A11i);
        u3_pair(Sr[4], Si[4], Sr[6], Si[6], Bm00r, Bm00i, Bm01r, Bm01i, Bm10r, Bm10i, Bm11r, Bm11i);
        u3_pair(Sr[5], Si[5], Sr[7], Si[7], Bm00r, Bm00i, Bm01r, Bm01i, Bm10r, Bm10i, Bm11r, Bm11i);
    }
    // ===== F3 = CRY_1(2) * U3_1(3): ctrl q2 (k bit1), tgt q3 (k bit0) =====
    {
        LOADM(A, 124); LOADM(Bm, 204);
        u3_pair(Sr[0], Si[0], Sr[1], Si[1], A00r, A00i, A01r, A01i, A10r, A10i, A11r, A11i);
        u3_pair(Sr[4], Si[4], Sr[5], Si[5], A00r, A00i, A01r, A01i, A10r, A10i, A11r, A11i);
        u3_pair(Sr[2], Si[2], Sr[3], Si[3], Bm00r, Bm00i, Bm01r, Bm01i, Bm10r, Bm10i, Bm11r, Bm11i);
        u3_pair(Sr[6], Si[6], Sr[7], Si[7], Bm00r, Bm00i, Bm01r, Bm01i, Bm10r, Bm10i, Bm11r, Bm11i);
    }
    // ===== F4 = CRY_1(3) * U3_1(4): ctrl q3 (k bit0), tgt q4 (lane bit5), block form =====
    {
        LOADM(A, 132); LOADM(Bm, 212);
        const bool hi = (lane >> 5) & 1;
        const float eAr = hi ? A10r : A00r, eAi = hi ? A10i : A00i;
        const float fAr = hi ? A11r : A01r, fAi = hi ? A11i : A01i;
        const float eBr = hi ? Bm10r : Bm00r, eBi = hi ? Bm10i : Bm00i;
        const float fBr = hi ? Bm11r : Bm01r, fBi = hi ? Bm11i : Bm01i;
#pragma unroll
        for (int k = 0; k < 8; ++k) {
            const float er = (k & 1) ? eBr : eAr, ei = (k & 1) ? eBi : eAi;
            const float fr = (k & 1) ? fBr : fAr, fi = (k & 1) ? fBi : fAi;
            const VPair R = blkswap2<5>(Sr[k], lane);
            const VPair I = blkswap2<5>(Si[k], lane);
            Sr[k] = er * R.V0 - ei * I.V0 + fr * R.V1 - fi * I.V1;
            Si[k] = er * I.V0 + ei * R.V0 + fr * I.V1 + fi * R.V1;
        }
    }
    // ===== F5 = CRY_1(4) * U3_1(5): ctrl lane bit5, tgt lane bit4, block form =====
    {
        LOADM(A, 140); LOADM(Bm, 220);
        const bool ctrl = (lane >> 5) & 1;
        const bool hi = (lane >> 4) & 1;
        const float M00r = ctrl ? Bm00r : A00r, M00i = ctrl ? Bm00i : A00i;
        const float M01r = ctrl ? Bm01r : A01r, M01i = ctrl ? Bm01i : A01i;
        const float M10r = ctrl ? Bm10r : A10r, M10i = ctrl ? Bm10i : A10i;
        const float M11r = ctrl ? Bm11r : A11r, M11i = ctrl ? Bm11i : A11i;
        const float er = hi ? M10r : M00r, ei = hi ? M10i : M00i;
        const float fr = hi ? M11r : M01r, fi = hi ? M11i : M01i;
        gate_blk_full<4>(Sr, Si, lane, er, ei, fr, fi);
    }
    // ===== F6..F9: all-DPP lane-bit gates =====
    {
        LOADM(A, 148); LOADM(Bm, 228);       // ctrl bit4, tgt bit3
        const bool ctrl = (lane >> 4) & 1;
        const bool hi = (lane >> 3) & 1;
        const float M00r = ctrl ? Bm00r : A00r, M00i = ctrl ? Bm00i : A00i;
        const float M01r = ctrl ? Bm01r : A01r, M01i = ctrl ? Bm01i : A01i;
        const float M10r = ctrl ? Bm10r : A10r, M10i = ctrl ? Bm10i : A10i;
        const float M11r = ctrl ? Bm11r : A11r, M11i = ctrl ? Bm11i : A11i;
        const float dr = hi ? M11r : M00r, di = hi ? M11i : M00i;
        const float orr = hi ? M10r : M01r, oii = hi ? M10i : M01i;
        gate_dpp_full<3>(Sr, Si, dr, di, orr, oii);
    }
    {
        LOADM(A, 156); LOADM(Bm, 236);       // ctrl bit3, tgt bit2 (2-DPP xor4)
        const bool ctrl = (lane >> 3) & 1;
        const bool hi = (lane >> 2) & 1;
        const float M00r = ctrl ? Bm00r : A00r, M00i = ctrl ? Bm00i : A00i;
        const float M01r = ctrl ? Bm01r : A01r, M01i = ctrl ? Bm01i : A01i;
        const float M10r = ctrl ? Bm10r : A10r, M10i = ctrl ? Bm10i : A10i;
        const float M11r = ctrl ? Bm11r : A11r, M11i = ctrl ? Bm11i : A11i;
        const float dr = hi ? M11r : M00r, di = hi ? M11i : M00i;
        const float orr = hi ? M10r : M01r, oii = hi ? M10i : M01i;
        gate_dpp_full<2>(Sr, Si, dr, di, orr, oii);
    }
    {
        LOADM(A, 164); LOADM(Bm, 244);       // ctrl bit2, tgt bit1
        const bool ctrl = (lane >> 2) & 1;
        const bool hi = (lane >> 1) & 1;
        const float M00r = ctrl ? Bm00r : A00r, M00i = ctrl ? Bm00i : A00i;
        const float M01r = ctrl ? Bm01r : A01r, M01i = ctrl ? Bm01i : A01i;
        const float M10r = ctrl ? Bm10r : A10r, M10i = ctrl ? Bm10i : A10i;
        const float M11r = ctrl ? Bm11r : A11r, M11i = ctrl ? Bm11i : A11i;
        const float dr = hi ? M11r : M00r, di = hi ? M11i : M00i;
        const float orr = hi ? M10r : M01r, oii = hi ? M10i : M01i;
        gate_dpp_full<1>(Sr, Si, dr, di, orr, oii);
    }
    {
        LOADM(A, 172); LOADM(Bm, 252);       // ctrl bit1, tgt bit0
        const bool ctrl = (lane >> 1) & 1;
        const bool hi = lane & 1;
        const float M00r = ctrl ? Bm00r : A00r, M00i = ctrl ? Bm00i : A00i;
        const float M01r = ctrl ? Bm01r : A01r, M01i = ctrl ? Bm01i : A01i;
        const float M10r = ctrl ? Bm10r : A10r, M10i = ctrl ? Bm10i : A10i;
        const float M11r = ctrl ? Bm11r : A11r, M11i = ctrl ? Bm11i : A11i;
        const float dr = hi ? M11r : M00r, di = hi ? M11i : M00i;
        const float orr = hi ? M10r : M01r, oii = hi ? M10i : M01i;
        gate_dpp_full<0>(Sr, Si, dr, di, orr, oii);
    }
    // ===== CRY_1(9): ctrl q9 (lane bit0), tgt q0 (comp) =====
    {
        const float2 C = *(const float2*)&cs[98];
        const bool ctrl = lane & 1;
        const float cl = ctrl ? C.x : 1.0f;
        const float sl = ctrl ? C.y : 0.0f;
        const v2f C2 = {cl, cl};
        const v2f S2 = {-sl, sl};
#pragma unroll
        for (int k = 0; k < 8; ++k) {
            const v2f Ar = Sr[k], Ai = Si[k];
            Sr[k] = C2 * Ar + S2 * Ar.yx;
            Si[k] = C2 * Ai + S2 * Ai.yx;
        }
    }

    // ===== measurement =====
    v2f P[8];
    float ptot = 0.0f, z0p = 0.0f, z1p = 0.0f, z2p = 0.0f, z3p = 0.0f;
#pragma unroll
    for (int k = 0; k < 8; ++k) {
        P[k] = Sr[k] * Sr[k] + Si[k] * Si[k];
        const float sk = P[k].x + P[k].y;
        ptot += sk;
        z0p += P[k].x - P[k].y;
        z1p += ((k >> 2) & 1) ? -sk : sk;   // qubit1 = k bit2
        z2p += ((k >> 1) & 1) ? -sk : sk;   // qubit2 = k bit1
        z3p += (k & 1) ? -sk : sk;          // qubit3 = k bit0
    }
    // Walsh chain on ptot for lane-bit qubits (qubit q at lane bit 9-q)
    float d0, d1, d2, d3, d4, d5;
    {
        float a = ptot, p;
        p = partner1<0>(a); d0 = a - p; a += p;
        p = partner1<1>(a); d1 = a - p; a += p;
        p = partner1<2>(a); d2 = a - p; a += p;
        p = partner1<3>(a); d3 = a - p; a += p;
        { const FPair o = blkswap1<4>(a, lane); d4 = o.v0 - o.v1; a = o.v0 + o.v1; }
        { const FPair o = blkswap1<5>(a, lane); d5 = o.v0 - o.v1; }
    }
    // packed reduction for the four k/comp-qubit partials
    const v2f z01 = vplus_reduce((v2f){z0p, z1p}, lane);
    const v2f z23 = vplus_reduce((v2f){z2p, z3p}, lane);
    float z[NQ];
    z[0] = z01.x; z[1] = z01.y; z[2] = z23.x; z[3] = z23.y;
    z[4] = d5;                          // lane bit5
    z[5] = plus_reduce<5>(d4, lane);    // lane bit4
    z[6] = plus_reduce<4>(d3, lane);    // lane bit3
    z[7] = plus_reduce<3>(d2, lane);    // lane bit2
    z[8] = plus_reduce<2>(d1, lane);    // lane bit1
    z[9] = plus_reduce<1>(d0, lane);    // lane bit0

    if (lane == 0) {
#pragma unroll
        for (int q = 0; q < NQ; ++q) out[b * NQ + q] = z[q];
    }
}

extern "C" void kernel_launch(void* const* d_in, const int* in_sizes, int n_in,
                              void* d_out, int out_size, void* d_ws, size_t ws_size,
                              hipStream_t stream) {
    const float* inputs  = (const float*)d_in[0];
    const float* weights = (const float*)d_in[1];
    float* out = (float*)d_out;
    const int B = in_sizes[0] / NQ;

    qsim<<<(B + 3) / 4, 256, 0, stream>>>(inputs, weights, out, B);
}

// Round 11
// 83.713 us; speedup vs baseline: 1.0102x; 1.0102x over previous
//
#include <hip/hip_runtime.h>
#include <math.h>

#define NQ 10
typedef float v2f __attribute__((ext_vector_type(2)));

#if defined(__has_builtin)
#if __has_builtin(__builtin_amdgcn_permlane16_swap) && __has_builtin(__builtin_amdgcn_permlane32_swap)
#define HAVE_PL 1
#endif
#endif

template<int CTRL>
__device__ __forceinline__ float dppf(float x) {
    return __int_as_float(__builtin_amdgcn_update_dpp(
        __float_as_int(x), __float_as_int(x), CTRL, 0xF, 0xF, true));
}
template<int OFS>
__device__ __forceinline__ float swzf(float x) {
    return __int_as_float(__builtin_amdgcn_ds_swizzle(__float_as_int(x), OFS));
}
__device__ __forceinline__ float bperm(int idx, float x) {
    return __int_as_float(__builtin_amdgcn_ds_bpermute(idx, __float_as_int(x)));
}

// partner on lane-bit P for P=0..3 — all VALU DPP:
template<int P>
__device__ __forceinline__ float partner1(float x) {
    if constexpr (P == 0) return dppf<0xB1>(x);            // quad_perm xor1
    else if constexpr (P == 1) return dppf<0x4E>(x);       // quad_perm xor2
    else if constexpr (P == 2) return dppf<0x1B>(dppf<0x141>(x)); // xor4 = xor7 then xor3
    else return dppf<0x128>(x);                            // row_ror:8 = xor8
}
template<int P>
__device__ __forceinline__ v2f partner2(v2f v) {
    v2f r; r.x = partner1<P>(v.x); r.y = partner1<P>(v.y); return r;
}

// block swap on lane-bit P (P=4 or 5): {v0,v1} = pair members with bit P = 0 / 1
struct FPair { float v0, v1; };
template<int P>
__device__ __forceinline__ FPair blkswap1(float x, int lane) {
    FPair o;
#ifdef HAVE_PL
    if constexpr (P == 4) {
        auto r = __builtin_amdgcn_permlane16_swap(__float_as_uint(x), __float_as_uint(x), false, false);
        o.v0 = __uint_as_float(r[0]);
        o.v1 = __uint_as_float(r[1]);
    } else {
        auto r = __builtin_amdgcn_permlane32_swap(__float_as_uint(x), __float_as_uint(x), false, false);
        o.v0 = __uint_as_float(r[0]);
        o.v1 = __uint_as_float(r[1]);
    }
#else
    const float p = (P == 4) ? swzf<0x401F>(x) : bperm((lane ^ 32) << 2, x);
    const bool hi = (lane >> P) & 1;
    o.v0 = hi ? p : x;
    o.v1 = hi ? x : p;
#endif
    return o;
}
struct VPair { v2f V0, V1; };
template<int P>
__device__ __forceinline__ VPair blkswap2(v2f x, int lane) {
    const FPair a = blkswap1<P>(x.x, lane);
    const FPair b = blkswap1<P>(x.y, lane);
    VPair o;
    o.V0 = (v2f){a.v0, b.v0};
    o.V1 = (v2f){a.v1, b.v1};
    return o;
}
template<int P>
__device__ __forceinline__ float blkadd(float x, int lane) {
    const FPair o = blkswap1<P>(x, lane);
    return o.v0 + o.v1;
}

// ---- gate bodies ----
template<int P>
__device__ __forceinline__ void gate_blk_full(v2f (&Sr)[8], v2f (&Si)[8], int lane,
                                              float er, float ei, float fr, float fi) {
#pragma unroll
    for (int k = 0; k < 8; ++k) {
        const VPair R = blkswap2<P>(Sr[k], lane);
        const VPair I = blkswap2<P>(Si[k], lane);
        Sr[k] = er * R.V0 - ei * I.V0 + fr * R.V1 - fi * I.V1;
        Si[k] = er * I.V0 + ei * R.V0 + fr * I.V1 + fi * R.V1;
    }
}
template<int P>
__device__ __forceinline__ void gate_blk_real(v2f (&Sr)[8], v2f (&Si)[8], int lane,
                                              float e, float f) {
#pragma unroll
    for (int k = 0; k < 8; ++k) {
        const VPair R = blkswap2<P>(Sr[k], lane);
        const VPair I = blkswap2<P>(Si[k], lane);
        Sr[k] = e * R.V0 + f * R.V1;
        Si[k] = e * I.V0 + f * I.V1;
    }
}
template<int P>
__device__ __forceinline__ void gate_dpp_full(v2f (&Sr)[8], v2f (&Si)[8],
                                              float dr, float di, float orr, float oii) {
#pragma unroll
    for (int k = 0; k < 8; ++k) {
        const v2f mr = Sr[k], mi = Si[k];
        const v2f pr = partner2<P>(mr);
        const v2f pi = partner2<P>(mi);
        Sr[k] = dr * mr - di * mi + orr * pr - oii * pi;
        Si[k] = dr * mi + di * mr + orr * pi + oii * pr;
    }
}
template<int P>
__device__ __forceinline__ void gate_dpp_real(v2f (&Sr)[8], v2f (&Si)[8],
                                              float cl, float sgn) {
#pragma unroll
    for (int k = 0; k < 8; ++k) {
        const v2f pr = partner2<P>(Sr[k]);
        const v2f pi = partner2<P>(Si[k]);
        Sr[k] = cl * Sr[k] + sgn * pr;
        Si[k] = cl * Si[k] + sgn * pi;
    }
}
__device__ __forceinline__ void u3_pair(v2f& a0r, v2f& a0i, v2f& a1r, v2f& a1i,
                                        float u00r, float u00i, float u01r, float u01i,
                                        float u10r, float u10i, float u11r, float u11i) {
    v2f n0r = u00r * a0r - u00i * a0i + u01r * a1r - u01i * a1i;
    v2f n0i = u00r * a0i + u00i * a0r + u01r * a1i + u01i * a1r;
    v2f n1r = u10r * a0r - u10i * a0i + u11r * a1r - u11i * a1i;
    v2f n1i = u10r * a0i + u10i * a0r + u11r * a1i + u11i * a1r;
    a0r = n0r; a0i = n0i; a1r = n1r; a1i = n1i;
}
__device__ __forceinline__ void ry_pair(v2f& a0r, v2f& a0i, v2f& a1r, v2f& a1i,
                                        float c, float s) {
    v2f n0r = c * a0r - s * a1r;
    v2f n0i = c * a0i - s * a1i;
    v2f n1r = s * a0r + c * a1r;
    v2f n1i = s * a0i + c * a1i;
    a0r = n0r; a0i = n0i; a1r = n1r; a1i = n1i;
}
__device__ __forceinline__ void cmul(float& xr, float& xi, float br, float bi) {
    const float nr = xr * br - xi * bi;
    const float ni = xr * bi + xi * br;
    xr = nr; xi = ni;
}

template<int FROM>
__device__ __forceinline__ float plus_reduce(float x, int lane) {
    if constexpr (FROM <= 0) x += partner1<0>(x);
    if constexpr (FROM <= 1) x += partner1<1>(x);
    if constexpr (FROM <= 2) x += partner1<2>(x);
    if constexpr (FROM <= 3) x += partner1<3>(x);
    if constexpr (FROM <= 4) x = blkadd<4>(x, lane);
    x = blkadd<5>(x, lane);
    return x;
}
__device__ __forceinline__ v2f vplus_reduce(v2f x, int lane) {
    x += partner2<0>(x);
    x += partner2<1>(x);
    x += partner2<2>(x);
    x += partner2<3>(x);
    { const VPair o = blkswap2<4>(x, lane); x = o.V0 + o.V1; }
    { const VPair o = blkswap2<5>(x, lane); x = o.V0 + o.V1; }
    return x;
}

#define LOADM(P, base) \
    const float4 P##va = *(const float4*)&cs[(base)]; \
    const float4 P##vb = *(const float4*)&cs[(base) + 4]; \
    const float P##00r = P##va.x, P##00i = P##va.y, P##01r = P##va.z, P##01i = P##va.w, \
                P##10r = P##vb.x, P##10i = P##vb.y, P##11r = P##vb.z, P##11i = P##vb.w;

// Block-shared coefficient slice (cs[]) float layout:
//  [0..79]    U3_0 rows as float2 by (q, j)
//  [80..97]   CRY_0 e=0..8: (c,s) at 80+2e
//  [98..99]   CRY_1 e=9: (c,s)
//  [100..179] A_q = U3_1(q), 8 floats at 100+8q
//  [180..259] B_q: q=0: A_0*RY(w39); q>=1: RY(w[70+q-1])*A_q ; at 180+8q
//  [260..275] F0 table: A_0(8 std), B_0(8 std); lane reads 2xb128 at 260+ctrl*8
//  [276..355] F5..F9 tables (g=0..4): base 276+16g, idx=(ctrl*2+hi)*4
//             F5 (g=0): natural rows (er,ei,fr,fi); F6-9: diag-first (dr,di,or,oi)
//  [356..371] F4 table: [A r0, B r0, A r1, B r1]; lane reads 2xb128 at 356+hi*8
//  [372..411] e4..e8 coef-pair tables (g=0..4): base 372+8g, idx=(ctrl*2+hi)*2
//             e4: (e,f) variants; e5-8: (cl,sgn) variants
__global__ __launch_bounds__(256) void qsim(const float* __restrict__ in,
                                            const float* __restrict__ w,
                                            float* __restrict__ out, int B) {
    __shared__ __attribute__((aligned(16))) float csh[416];
    __shared__ __attribute__((aligned(16))) float tsh[4 * 40];
    const int lane = threadIdx.x & 63;
    const int wave = threadIdx.x >> 6;
    int b = blockIdx.x * 4 + wave;
    b = __builtin_amdgcn_readfirstlane(b);
    float* cs = csh;

    // ===== coefficient generation: wave 0 only =====
    if (wave == 0) {
        const int q = (lane < 20) ? (lane % 10) : ((lane >= 40 && lane < 50) ? lane - 40 : 0);
        const int wb = (lane < 10) ? 3 * lane : 40 + 3 * q;
        const float phi = w[wb], theta = w[wb + 1], omega = w[wb + 2];
        float u0, u1, u2, u3, u4, u5, u6, u7;
        {
            const float ct = __cosf(0.5f * theta), st = __sinf(0.5f * theta);
            const float apo = 0.5f * (phi + omega), amo = 0.5f * (phi - omega);
            const float capo = __cosf(apo), sapo = __sinf(apo);
            const float camo = __cosf(amo), samo = __sinf(amo);
            u0 =  capo * ct;  u1 = -sapo * ct;   // U00
            u2 = -camo * st;  u3 = -samo * st;   // U01
            u4 =  camo * st;  u5 = -samo * st;   // U10
            u6 =  capo * ct;  u7 =  sapo * ct;   // U11
        }
        const int cidx = (lane >= 20 && lane < 29) ? 30 + (lane - 20)
                       : (lane == 29) ? 79
                       : (lane == 40) ? 39
                       : 70 + (q - 1) + (q == 0 ? 1 : 0);
        const float th = 0.5f * w[cidx];
        const float c2 = __cosf(th), s2 = __sinf(th);
        if (lane >= 40 && lane < 50) {
            const bool r = (lane == 40);       // B_0 = A*RY (right); else B_q = RY*A (left)
            const float p0 = r ? (u0 * c2 + u2 * s2) : (c2 * u0 - s2 * u4);
            const float p1 = r ? (u1 * c2 + u3 * s2) : (c2 * u1 - s2 * u5);
            const float p2 = r ? (u2 * c2 - u0 * s2) : (c2 * u2 - s2 * u6);
            const float p3 = r ? (u3 * c2 - u1 * s2) : (c2 * u3 - s2 * u7);
            const float p4 = r ? (u4 * c2 + u6 * s2) : (s2 * u0 + c2 * u4);
            const float p5 = r ? (u5 * c2 + u7 * s2) : (s2 * u1 + c2 * u5);
            const float p6 = r ? (u6 * c2 - u4 * s2) : (s2 * u2 + c2 * u6);
            const float p7 = r ? (u7 * c2 - u5 * s2) : (s2 * u3 + c2 * u7);
            u0 = p0; u1 = p1; u2 = p2; u3 = p3; u4 = p4; u5 = p5; u6 = p6; u7 = p7;
        }
        if (lane < 10) {                       // U3_0 row format
            *(float4*)&cs[lane * 8]     = (float4){u0, u2, u1, u3};
            *(float4*)&cs[lane * 8 + 4] = (float4){u4, u6, u5, u7};
        } else if (lane < 20) {                // A_q + tables
            const int qq = lane - 10;
            *(float4*)&cs[100 + qq * 8]     = (float4){u0, u1, u2, u3};
            *(float4*)&cs[100 + qq * 8 + 4] = (float4){u4, u5, u6, u7};
            if (qq == 0) {                     // F0 A half
                *(float4*)&cs[260] = (float4){u0, u1, u2, u3};
                *(float4*)&cs[264] = (float4){u4, u5, u6, u7};
            } else if (qq == 4) {              // F4 A rows
                *(float4*)&cs[356] = (float4){u0, u1, u2, u3};
                *(float4*)&cs[364] = (float4){u4, u5, u6, u7};
            } else if (qq >= 5) {              // F5..F9 A variants
                const int g = qq - 5;
                if (g == 0) {                  // F5: natural rows
                    *(float4*)&cs[276 + 0] = (float4){u0, u1, u2, u3};
                    *(float4*)&cs[276 + 4] = (float4){u4, u5, u6, u7};
                } else {                       // F6-9: v0 natural, v1 diag-first
                    *(float4*)&cs[276 + 16 * g + 0] = (float4){u0, u1, u2, u3};
                    *(float4*)&cs[276 + 16 * g + 4] = (float4){u6, u7, u4, u5};
                }
            }
        } else if (lane < 30) {                // CRY pairs + e4..e8 tables
            const int off = (lane < 29) ? 80 + 2 * (lane - 20) : 98;
            *(float2*)&cs[off] = (float2){c2, s2};
            if (lane >= 24 && lane < 29) {
                const int g = lane - 24;       // e4..e8
                float2 v0, v1, v2, v3;
                if (g == 0) { v0 = (float2){1.f, 0.f}; v1 = (float2){0.f, 1.f};
                              v2 = (float2){c2, -s2};  v3 = (float2){s2, c2}; }
                else        { v0 = (float2){1.f, 0.f}; v1 = (float2){1.f, 0.f};
                              v2 = (float2){c2, -s2};  v3 = (float2){c2, s2}; }
                *(float2*)&cs[372 + 8 * g + 0] = v0;
                *(float2*)&cs[372 + 8 * g + 2] = v1;
                *(float2*)&cs[372 + 8 * g + 4] = v2;
                *(float2*)&cs[372 + 8 * g + 6] = v3;
            }
        } else if (lane >= 40 && lane < 50) {  // B_q + tables
            *(float4*)&cs[180 + q * 8]     = (float4){u0, u1, u2, u3};
            *(float4*)&cs[180 + q * 8 + 4] = (float4){u4, u5, u6, u7};
            if (q == 0) {                      // F0 B half
                *(float4*)&cs[268] = (float4){u0, u1, u2, u3};
                *(float4*)&cs[272] = (float4){u4, u5, u6, u7};
            } else if (q == 4) {               // F4 B rows
                *(float4*)&cs[360] = (float4){u0, u1, u2, u3};
                *(float4*)&cs[368] = (float4){u4, u5, u6, u7};
            } else if (q >= 5) {               // F5..F9 B variants
                const int g = q - 5;
                if (g == 0) {
                    *(float4*)&cs[276 + 8]  = (float4){u0, u1, u2, u3};
                    *(float4*)&cs[276 + 12] = (float4){u4, u5, u6, u7};
                } else {
                    *(float4*)&cs[276 + 16 * g + 8]  = (float4){u0, u1, u2, u3};
                    *(float4*)&cs[276 + 16 * g + 12] = (float4){u6, u7, u4, u5};
                }
            }
        }
    }
    __syncthreads();
    if (b >= B) return;

    // ---- distributed input fold: lane = q*4 + j computes t-component j of qubit q ----
    if (lane < 40) {
        const int q = lane >> 2;
        float x = in[b * NQ + q];
        x = fminf(fmaxf(x, 0.0f), 1.0f);
        const float a = 0.5f * 3.14159265358979323846f * x;
        const float ca = __cosf(a), sa = __sinf(a);
        const float M0 = cs[lane * 2], M1 = cs[lane * 2 + 1];
        tsh[wave * 40 + lane] = M0 * ca + M1 * sa;
    }
    const int base = wave * 40;

    float wr, wi;
    {
        const int bit = lane & 1;
        const float2 v = *(const float2*)&tsh[base + 9 * 4 + (bit << 1)];
        wr = v.x; wi = v.y;
    }
#pragma unroll
    for (int j = 1; j < 6; ++j) {
        const int bit = (lane >> j) & 1;
        const float2 v = *(const float2*)&tsh[base + (9 - j) * 4 + (bit << 1)];
        cmul(wr, wi, v.x, v.y);
    }
    const float4 T0 = *(const float4*)&tsh[base + 0];
    const float4 T1 = *(const float4*)&tsh[base + 4];
    const float4 T2 = *(const float4*)&tsh[base + 8];
    const float4 T3 = *(const float4*)&tsh[base + 12];

    float vr[4], vi[4];
    { float r = T1.x, i2 = T1.y; vr[0] = r * T2.x - i2 * T2.y; vi[0] = r * T2.y + i2 * T2.x;
                                  vr[1] = r * T2.z - i2 * T2.w; vi[1] = r * T2.w + i2 * T2.z; }
    { float r = T1.z, i2 = T1.w; vr[2] = r * T2.x - i2 * T2.y; vi[2] = r * T2.y + i2 * T2.x;
                                  vr[3] = r * T2.z - i2 * T2.w; vi[3] = r * T2.w + i2 * T2.z; }
    v2f Sr[8], Si[8];
    const v2f T0r = {T0.x, T0.z};
    const v2f T0i = {T0.y, T0.w};
#pragma unroll
    for (int k = 0; k < 8; ++k) {
        const int hv = k >> 1;
        const float t3r = (k & 1) ? T3.z : T3.x;
        const float t3i = (k & 1) ? T3.w : T3.y;
        float kr = vr[hv] * t3r - vi[hv] * t3i;
        float ki = vr[hv] * t3i + vi[hv] * t3r;
        cmul(kr, ki, wr, wi);
        Sr[k] = kr * T0r - ki * T0i;
        Si[k] = kr * T0i + ki * T0r;
    }

    // ===== CRY_0 ring, e = 0..8 =====
    {   // e0: ctrl q0 (comp), tgt q1 (k bit2)
        const float2 C = *(const float2*)&cs[80];
        const v2f cv = {1.0f, C.x};
        const v2f sv = {0.0f, C.y};
#pragma unroll
        for (int k0 = 0; k0 < 4; ++k0) {
            const int k1 = k0 | 4;
            v2f n0r = cv * Sr[k0] - sv * Sr[k1];
            v2f n0i = cv * Si[k0] - sv * Si[k1];
            v2f n1r = sv * Sr[k0] + cv * Sr[k1];
            v2f n1i = sv * Si[k0] + cv * Si[k1];
            Sr[k0] = n0r; Si[k0] = n0i; Sr[k1] = n1r; Si[k1] = n1i;
        }
    }
    {   // e1: ctrl q1 (k bit2), tgt q2 (k bit1)
        const float2 C = *(const float2*)&cs[82];
        ry_pair(Sr[4], Si[4], Sr[6], Si[6], C.x, C.y);
        ry_pair(Sr[5], Si[5], Sr[7], Si[7], C.x, C.y);
    }
    {   // e2: ctrl q2 (k bit1), tgt q3 (k bit0)
        const float2 C = *(const float2*)&cs[84];
        ry_pair(Sr[2], Si[2], Sr[3], Si[3], C.x, C.y);
        ry_pair(Sr[6], Si[6], Sr[7], Si[7], C.x, C.y);
    }
    {   // e3: ctrl q3 (k bit0) -> odd k only; tgt q4 (lane bit5), block form
        const float2 C = *(const float2*)&cs[86];
        const bool hi = (lane >> 5) & 1;
        const float e = hi ? C.y : C.x;
        const float f = hi ? C.x : -C.y;
#pragma unroll
        for (int k = 1; k < 8; k += 2) {
            const VPair R = blkswap2<5>(Sr[k], lane);
            const VPair I = blkswap2<5>(Si[k], lane);
            Sr[k] = e * R.V0 + f * R.V1;
            Si[k] = e * I.V0 + f * I.V1;
        }
    }
    {   // e4: ctrl bit5, tgt bit4 — table fetch
        const int idx = (((lane >> 5) & 1) << 1) | ((lane >> 4) & 1);
        const float2 ef = *(const float2*)&cs[372 + idx * 2];
        gate_blk_real<4>(Sr, Si, lane, ef.x, ef.y);
    }
    {   // e5: ctrl bit4, tgt bit3
        const int idx = (((lane >> 4) & 1) << 1) | ((lane >> 3) & 1);
        const float2 cv = *(const float2*)&cs[380 + idx * 2];
        gate_dpp_real<3>(Sr, Si, cv.x, cv.y);
    }
    {   // e6: ctrl bit3, tgt bit2
        const int idx = (((lane >> 3) & 1) << 1) | ((lane >> 2) & 1);
        const float2 cv = *(const float2*)&cs[388 + idx * 2];
        gate_dpp_real<2>(Sr, Si, cv.x, cv.y);
    }
    {   // e7: ctrl bit2, tgt bit1
        const int idx = (((lane >> 2) & 1) << 1) | ((lane >> 1) & 1);
        const float2 cv = *(const float2*)&cs[396 + idx * 2];
        gate_dpp_real<1>(Sr, Si, cv.x, cv.y);
    }
    {   // e8: ctrl bit1, tgt bit0
        const int idx = (((lane >> 1) & 1) << 1) | (lane & 1);
        const float2 cv = *(const float2*)&cs[404 + idx * 2];
        gate_dpp_real<0>(Sr, Si, cv.x, cv.y);
    }

    // ===== F0 = U3_1(0) * CRY_0(9): ctrl q9 (lane bit0), tgt q0 (comp) =====
    {
        const int ctrl = lane & 1;
        const float4 ma = *(const float4*)&cs[260 + ctrl * 8];
        const float4 mb = *(const float4*)&cs[264 + ctrl * 8];
        const v2f Dr = {ma.x, mb.z}, Di = {ma.y, mb.w};
        const v2f Or = {ma.z, mb.x}, Oi = {ma.w, mb.y};
#pragma unroll
        for (int k = 0; k < 8; ++k) {
            const v2f Ar = Sr[k], Ai = Si[k];
            const v2f Br = Ar.yx, Bi = Ai.yx;
            Sr[k] = Dr * Ar - Di * Ai + Or * Br - Oi * Bi;
            Si[k] = Dr * Ai + Di * Ar + Or * Bi + Oi * Br;
        }
    }
    // ===== F1 = CRY_1(0) * U3_1(1): ctrl q0 (comp), tgt q1 (k bit2) =====
    {
        LOADM(A, 108); LOADM(Bm, 188);
        const v2f u00r = {A00r, Bm00r}, u00i = {A00i, Bm00i};
        const v2f u01r = {A01r, Bm01r}, u01i = {A01i, Bm01i};
        const v2f u10r = {A10r, Bm10r}, u10i = {A10i, Bm10i};
        const v2f u11r = {A11r, Bm11r}, u11i = {A11i, Bm11i};
#pragma unroll
        for (int k0 = 0; k0 < 4; ++k0) {
            const int k1 = k0 | 4;
            v2f n0r = u00r * Sr[k0] - u00i * Si[k0] + u01r * Sr[k1] - u01i * Si[k1];
            v2f n0i = u00r * Si[k0] + u00i * Sr[k0] + u01r * Si[k1] + u01i * Sr[k1];
            v2f n1r = u10r * Sr[k0] - u10i * Si[k0] + u11r * Sr[k1] - u11i * Si[k1];
            v2f n1i = u10r * Si[k0] + u10i * Sr[k0] + u11r * Si[k1] + u11i * Sr[k1];
            Sr[k0] = n0r; Si[k0] = n0i; Sr[k1] = n1r; Si[k1] = n1i;
        }
    }
    // ===== F2 = CRY_1(1) * U3_1(2): ctrl q1 (k bit2), tgt q2 (k bit1) =====
    {
        LOADM(A, 116); LOADM(Bm, 196);
        u3_pair(Sr[0], Si[0], Sr[2], Si[2], A00r, A00i, A01r, A01i, A10r, A10i, A11r, A11i);
        u3_pair(Sr[1], Si[1], Sr[3], Si[3], A00r, A00i, A01r, A01i, A10r, A10i, A11r, A11i);
        u3_pair(Sr[4], Si[4], Sr[6], Si[6], Bm00r, Bm00i, Bm01r, Bm01i, Bm10r, Bm10i, Bm11r, Bm11i);
        u3_pair(Sr[5], Si[5], Sr[7], Si[7], Bm00r, Bm00i, Bm01r, Bm01i, Bm10r, Bm10i, Bm11r, Bm11i);
    }
    // ===== F3 = CRY_1(2) * U3_1(3): ctrl q2 (k bit1), tgt q3 (k bit0) =====
    {
        LOADM(A, 124); LOADM(Bm, 204);
        u3_pair(Sr[0], Si[0], Sr[1], Si[1], A00r, A00i, A01r, A01i, A10r, A10i, A11r, A11i);
        u3_pair(Sr[4], Si[4], Sr[5], Si[5], A00r, A00i, A01r, A01i, A10r, A10i, A11r, A11i);
        u3_pair(Sr[2], Si[2], Sr[3], Si[3], Bm00r, Bm00i, Bm01r, Bm01i, Bm10r, Bm10i, Bm11r, Bm11i);
        u3_pair(Sr[6], Si[6], Sr[7], Si[7], Bm00r, Bm00i, Bm01r, Bm01i, Bm10r, Bm10i, Bm11r, Bm11i);
    }
    // ===== F4 = CRY_1(3) * U3_1(4): ctrl q3 (k bit0), tgt q4 (lane bit5), block form =====
    {
        const int hi = (lane >> 5) & 1;
        const float4 ra = *(const float4*)&cs[356 + hi * 8];   // A row
        const float4 rb = *(const float4*)&cs[360 + hi * 8];   // B row
#pragma unroll
        for (int k = 0; k < 8; ++k) {
            const float er = (k & 1) ? rb.x : ra.x, ei = (k & 1) ? rb.y : ra.y;
            const float fr = (k & 1) ? rb.z : ra.z, fi = (k & 1) ? rb.w : ra.w;
            const VPair R = blkswap2<5>(Sr[k], lane);
            const VPair I = blkswap2<5>(Si[k], lane);
            Sr[k] = er * R.V0 - ei * I.V0 + fr * R.V1 - fi * I.V1;
            Si[k] = er * I.V0 + ei * R.V0 + fr * I.V1 + fi * R.V1;
        }
    }
    // ===== F5 = CRY_1(4) * U3_1(5): ctrl bit5, tgt bit4, block form — table fetch =====
    {
        const int idx = (((lane >> 5) & 1) << 1) | ((lane >> 4) & 1);
        const float4 r = *(const float4*)&cs[276 + idx * 4];
        gate_blk_full<4>(Sr, Si, lane, r.x, r.y, r.z, r.w);
    }
    // ===== F6..F9: DPP lane-bit gates — table fetch =====
    {
        const int idx = (((lane >> 4) & 1) << 1) | ((lane >> 3) & 1);
        const float4 r = *(const float4*)&cs[292 + idx * 4];
        gate_dpp_full<3>(Sr, Si, r.x, r.y, r.z, r.w);
    }
    {
        const int idx = (((lane >> 3) & 1) << 1) | ((lane >> 2) & 1);
        const float4 r = *(const float4*)&cs[308 + idx * 4];
        gate_dpp_full<2>(Sr, Si, r.x, r.y, r.z, r.w);
    }
    {
        const int idx = (((lane >> 2) & 1) << 1) | ((lane >> 1) & 1);
        const float4 r = *(const float4*)&cs[324 + idx * 4];
        gate_dpp_full<1>(Sr, Si, r.x, r.y, r.z, r.w);
    }
    {
        const int idx = (((lane >> 1) & 1) << 1) | (lane & 1);
        const float4 r = *(const float4*)&cs[340 + idx * 4];
        gate_dpp_full<0>(Sr, Si, r.x, r.y, r.z, r.w);
    }
    // ===== CRY_1(9): ctrl q9 (lane bit0), tgt q0 (comp) =====
    {
        const float2 C = *(const float2*)&cs[98];
        const bool ctrl = lane & 1;
        const float cl = ctrl ? C.x : 1.0f;
        const float sl = ctrl ? C.y : 0.0f;
        const v2f C2 = {cl, cl};
        const v2f S2 = {-sl, sl};
#pragma unroll
        for (int k = 0; k < 8; ++k) {
            const v2f Ar = Sr[k], Ai = Si[k];
            Sr[k] = C2 * Ar + S2 * Ar.yx;
            Si[k] = C2 * Ai + S2 * Ai.yx;
        }
    }

    // ===== measurement =====
    v2f P[8];
    float ptot = 0.0f, z0p = 0.0f, z1p = 0.0f, z2p = 0.0f, z3p = 0.0f;
#pragma unroll
    for (int k = 0; k < 8; ++k) {
        P[k] = Sr[k] * Sr[k] + Si[k] * Si[k];
        const float sk = P[k].x + P[k].y;
        ptot += sk;
        z0p += P[k].x - P[k].y;
        z1p += ((k >> 2) & 1) ? -sk : sk;
        z2p += ((k >> 1) & 1) ? -sk : sk;
        z3p += (k & 1) ? -sk : sk;
    }
    float d0, d1, d2, d3, d4, d5;
    {
        float a = ptot, p;
        p = partner1<0>(a); d0 = a - p; a += p;
        p = partner1<1>(a); d1 = a - p; a += p;
        p = partner1<2>(a); d2 = a - p; a += p;
        p = partner1<3>(a); d3 = a - p; a += p;
        { const FPair o = blkswap1<4>(a, lane); d4 = o.v0 - o.v1; a = o.v0 + o.v1; }
        { const FPair o = blkswap1<5>(a, lane); d5 = o.v0 - o.v1; }
    }
    const v2f z01 = vplus_reduce((v2f){z0p, z1p}, lane);
    const v2f z23 = vplus_reduce((v2f){z2p, z3p}, lane);
    float z[NQ];
    z[0] = z01.x; z[1] = z01.y; z[2] = z23.x; z[3] = z23.y;
    z[4] = d5;
    z[5] = plus_reduce<5>(d4, lane);
    z[6] = plus_reduce<4>(d3, lane);
    z[7] = plus_reduce<3>(d2, lane);
    z[8] = plus_reduce<2>(d1, lane);
    z[9] = plus_reduce<1>(d0, lane);

    if (lane == 0) {
#pragma unroll
        for (int q = 0; q < NQ; ++q) out[b * NQ + q] = z[q];
    }
}

extern "C" void kernel_launch(void* const* d_in, const int* in_sizes, int n_in,
                              void* d_out, int out_size, void* d_ws, size_t ws_size,
                              hipStream_t stream) {
    const float* inputs  = (const float*)d_in[0];
    const float* weights = (const float*)d_in[1];
    float* out = (float*)d_out;
    const int B = in_sizes[0] / NQ;

    qsim<<<(B + 3) / 4, 256, 0, stream>>>(inputs, weights, out, B);
}

// Round 12
// 80.950 us; speedup vs baseline: 1.0447x; 1.0341x over previous
//
#include <hip/hip_runtime.h>
#include <math.h>

#define NQ 10
typedef float v2f __attribute__((ext_vector_type(2)));
typedef _Float16 h2 __attribute__((ext_vector_type(2)));
#define H(x) ((_Float16)(x))

#if defined(__has_builtin)
#if __has_builtin(__builtin_amdgcn_permlane16_swap) && __has_builtin(__builtin_amdgcn_permlane32_swap)
#define HAVE_PL 1
#endif
#endif

__device__ __forceinline__ int h2i(h2 v) { return __builtin_bit_cast(int, v); }
__device__ __forceinline__ h2 ih2(int v) { return __builtin_bit_cast(h2, v); }

template<int CTRL>
__device__ __forceinline__ float dppf(float x) {
    return __int_as_float(__builtin_amdgcn_update_dpp(
        __float_as_int(x), __float_as_int(x), CTRL, 0xF, 0xF, true));
}
template<int CTRL>
__device__ __forceinline__ h2 dpph(h2 x) {
    return ih2(__builtin_amdgcn_update_dpp(h2i(x), h2i(x), CTRL, 0xF, 0xF, true));
}
template<int OFS>
__device__ __forceinline__ float swzf(float x) {
    return __int_as_float(__builtin_amdgcn_ds_swizzle(__float_as_int(x), OFS));
}
__device__ __forceinline__ float bperm(int idx, float x) {
    return __int_as_float(__builtin_amdgcn_ds_bpermute(idx, __float_as_int(x)));
}

// fp32 partner (measurement only)
template<int P>
__device__ __forceinline__ float partner1(float x) {
    if constexpr (P == 0) return dppf<0xB1>(x);
    else if constexpr (P == 1) return dppf<0x4E>(x);
    else if constexpr (P == 2) return dppf<0x1B>(dppf<0x141>(x));
    else return dppf<0x128>(x);
}
template<int P>
__device__ __forceinline__ v2f partner2(v2f v) {
    v2f r; r.x = partner1<P>(v.x); r.y = partner1<P>(v.y); return r;
}
// h2 partner: one DPP moves both components
template<int P>
__device__ __forceinline__ h2 partner_h(h2 x) {
    if constexpr (P == 0) return dpph<0xB1>(x);
    else if constexpr (P == 1) return dpph<0x4E>(x);
    else if constexpr (P == 2) return dpph<0x1B>(dpph<0x141>(x));
    else return dpph<0x128>(x);
}

// fp32 block swap (measurement)
struct FPair { float v0, v1; };
template<int P>
__device__ __forceinline__ FPair blkswap1(float x, int lane) {
    FPair o;
#ifdef HAVE_PL
    if constexpr (P == 4) {
        auto r = __builtin_amdgcn_permlane16_swap(__float_as_uint(x), __float_as_uint(x), false, false);
        o.v0 = __uint_as_float(r[0]);
        o.v1 = __uint_as_float(r[1]);
    } else {
        auto r = __builtin_amdgcn_permlane32_swap(__float_as_uint(x), __float_as_uint(x), false, false);
        o.v0 = __uint_as_float(r[0]);
        o.v1 = __uint_as_float(r[1]);
    }
#else
    const float p = (P == 4) ? swzf<0x401F>(x) : bperm((lane ^ 32) << 2, x);
    const bool hi = (lane >> P) & 1;
    o.v0 = hi ? p : x;
    o.v1 = hi ? x : p;
#endif
    return o;
}
struct VPair { v2f V0, V1; };
template<int P>
__device__ __forceinline__ VPair blkswap2(v2f x, int lane) {
    const FPair a = blkswap1<P>(x.x, lane);
    const FPair b = blkswap1<P>(x.y, lane);
    VPair o;
    o.V0 = (v2f){a.v0, b.v0};
    o.V1 = (v2f){a.v1, b.v1};
    return o;
}
template<int P>
__device__ __forceinline__ float blkadd(float x, int lane) {
    const FPair o = blkswap1<P>(x, lane);
    return o.v0 + o.v1;
}
// h2 block swap: one permlane per h2
struct HPair { h2 v0, v1; };
template<int P>
__device__ __forceinline__ HPair blkswap_h(h2 x, int lane) {
    HPair o;
#ifdef HAVE_PL
    if constexpr (P == 4) {
        auto r = __builtin_amdgcn_permlane16_swap((unsigned)h2i(x), (unsigned)h2i(x), false, false);
        o.v0 = ih2((int)r[0]);
        o.v1 = ih2((int)r[1]);
    } else {
        auto r = __builtin_amdgcn_permlane32_swap((unsigned)h2i(x), (unsigned)h2i(x), false, false);
        o.v0 = ih2((int)r[0]);
        o.v1 = ih2((int)r[1]);
    }
#else
    const int pv = (P == 4) ? __builtin_amdgcn_ds_swizzle(h2i(x), 0x401F)
                            : __builtin_amdgcn_ds_bpermute((lane ^ 32) << 2, h2i(x));
    const h2 p = ih2(pv);
    const bool hi = (lane >> P) & 1;
    o.v0 = hi ? p : x;
    o.v1 = hi ? x : p;
#endif
    return o;
}

// ---- h2 gate bodies ----
template<int P>
__device__ __forceinline__ void gate_blk_full_h(h2 (&Sr)[8], h2 (&Si)[8], int lane,
                                                _Float16 er, _Float16 ei, _Float16 fr, _Float16 fi) {
#pragma unroll
    for (int k = 0; k < 8; ++k) {
        const HPair R = blkswap_h<P>(Sr[k], lane);
        const HPair I = blkswap_h<P>(Si[k], lane);
        Sr[k] = er * R.v0 - ei * I.v0 + fr * R.v1 - fi * I.v1;
        Si[k] = er * I.v0 + ei * R.v0 + fr * I.v1 + fi * R.v1;
    }
}
template<int P>
__device__ __forceinline__ void gate_blk_real_h(h2 (&Sr)[8], h2 (&Si)[8], int lane,
                                                _Float16 e, _Float16 f) {
#pragma unroll
    for (int k = 0; k < 8; ++k) {
        const HPair R = blkswap_h<P>(Sr[k], lane);
        const HPair I = blkswap_h<P>(Si[k], lane);
        Sr[k] = e * R.v0 + f * R.v1;
        Si[k] = e * I.v0 + f * I.v1;
    }
}
template<int P>
__device__ __forceinline__ void gate_dpp_full_h(h2 (&Sr)[8], h2 (&Si)[8],
                                                _Float16 dr, _Float16 di, _Float16 orr, _Float16 oii) {
#pragma unroll
    for (int k = 0; k < 8; ++k) {
        const h2 mr = Sr[k], mi = Si[k];
        const h2 pr = partner_h<P>(mr);
        const h2 pi = partner_h<P>(mi);
        Sr[k] = dr * mr - di * mi + orr * pr - oii * pi;
        Si[k] = dr * mi + di * mr + orr * pi + oii * pr;
    }
}
template<int P>
__device__ __forceinline__ void gate_dpp_real_h(h2 (&Sr)[8], h2 (&Si)[8],
                                                _Float16 cl, _Float16 sgn) {
#pragma unroll
    for (int k = 0; k < 8; ++k) {
        const h2 pr = partner_h<P>(Sr[k]);
        const h2 pi = partner_h<P>(Si[k]);
        Sr[k] = cl * Sr[k] + sgn * pr;
        Si[k] = cl * Si[k] + sgn * pi;
    }
}
__device__ __forceinline__ void u3_pair_h(h2& a0r, h2& a0i, h2& a1r, h2& a1i,
                                          _Float16 u00r, _Float16 u00i, _Float16 u01r, _Float16 u01i,
                                          _Float16 u10r, _Float16 u10i, _Float16 u11r, _Float16 u11i) {
    h2 n0r = u00r * a0r - u00i * a0i + u01r * a1r - u01i * a1i;
    h2 n0i = u00r * a0i + u00i * a0r + u01r * a1i + u01i * a1r;
    h2 n1r = u10r * a0r - u10i * a0i + u11r * a1r - u11i * a1i;
    h2 n1i = u10r * a0i + u10i * a0r + u11r * a1i + u11i * a1r;
    a0r = n0r; a0i = n0i; a1r = n1r; a1i = n1i;
}
__device__ __forceinline__ void ry_pair_h(h2& a0r, h2& a0i, h2& a1r, h2& a1i,
                                          _Float16 c, _Float16 s) {
    h2 n0r = c * a0r - s * a1r;
    h2 n0i = c * a0i - s * a1i;
    h2 n1r = s * a0r + c * a1r;
    h2 n1i = s * a0i + c * a1i;
    a0r = n0r; a0i = n0i; a1r = n1r; a1i = n1i;
}
__device__ __forceinline__ void cmul(float& xr, float& xi, float br, float bi) {
    const float nr = xr * br - xi * bi;
    const float ni = xr * bi + xi * br;
    xr = nr; xi = ni;
}

template<int FROM>
__device__ __forceinline__ float plus_reduce(float x, int lane) {
    if constexpr (FROM <= 0) x += partner1<0>(x);
    if constexpr (FROM <= 1) x += partner1<1>(x);
    if constexpr (FROM <= 2) x += partner1<2>(x);
    if constexpr (FROM <= 3) x += partner1<3>(x);
    if constexpr (FROM <= 4) x = blkadd<4>(x, lane);
    x = blkadd<5>(x, lane);
    return x;
}
__device__ __forceinline__ v2f vplus_reduce(v2f x, int lane) {
    x += partner2<0>(x);
    x += partner2<1>(x);
    x += partner2<2>(x);
    x += partner2<3>(x);
    { const VPair o = blkswap2<4>(x, lane); x = o.V0 + o.V1; }
    { const VPair o = blkswap2<5>(x, lane); x = o.V0 + o.V1; }
    return x;
}

#define LOADM(P, base) \
    const float4 P##va = *(const float4*)&cs[(base)]; \
    const float4 P##vb = *(const float4*)&cs[(base) + 4]; \
    const float P##00r = P##va.x, P##00i = P##va.y, P##01r = P##va.z, P##01i = P##va.w, \
                P##10r = P##vb.x, P##10i = P##vb.y, P##11r = P##vb.z, P##11i = P##vb.w;

// Block-shared coefficient slice (cs[]) float layout — identical to R11.
__global__ __launch_bounds__(256) void qsim(const float* __restrict__ in,
                                            const float* __restrict__ w,
                                            float* __restrict__ out, int B) {
    __shared__ __attribute__((aligned(16))) float csh[416];
    __shared__ __attribute__((aligned(16))) float tsh[4 * 40];
    const int lane = threadIdx.x & 63;
    const int wave = threadIdx.x >> 6;
    int b = blockIdx.x * 4 + wave;
    b = __builtin_amdgcn_readfirstlane(b);
    float* cs = csh;

    // ===== coefficient generation: wave 0 only (fp32, same as R11) =====
    if (wave == 0) {
        const int q = (lane < 20) ? (lane % 10) : ((lane >= 40 && lane < 50) ? lane - 40 : 0);
        const int wb = (lane < 10) ? 3 * lane : 40 + 3 * q;
        const float phi = w[wb], theta = w[wb + 1], omega = w[wb + 2];
        float u0, u1, u2, u3, u4, u5, u6, u7;
        {
            const float ct = __cosf(0.5f * theta), st = __sinf(0.5f * theta);
            const float apo = 0.5f * (phi + omega), amo = 0.5f * (phi - omega);
            const float capo = __cosf(apo), sapo = __sinf(apo);
            const float camo = __cosf(amo), samo = __sinf(amo);
            u0 =  capo * ct;  u1 = -sapo * ct;
            u2 = -camo * st;  u3 = -samo * st;
            u4 =  camo * st;  u5 = -samo * st;
            u6 =  capo * ct;  u7 =  sapo * ct;
        }
        const int cidx = (lane >= 20 && lane < 29) ? 30 + (lane - 20)
                       : (lane == 29) ? 79
                       : (lane == 40) ? 39
                       : 70 + (q - 1) + (q == 0 ? 1 : 0);
        const float th = 0.5f * w[cidx];
        const float c2 = __cosf(th), s2 = __sinf(th);
        if (lane >= 40 && lane < 50) {
            const bool r = (lane == 40);
            const float p0 = r ? (u0 * c2 + u2 * s2) : (c2 * u0 - s2 * u4);
            const float p1 = r ? (u1 * c2 + u3 * s2) : (c2 * u1 - s2 * u5);
            const float p2 = r ? (u2 * c2 - u0 * s2) : (c2 * u2 - s2 * u6);
            const float p3 = r ? (u3 * c2 - u1 * s2) : (c2 * u3 - s2 * u7);
            const float p4 = r ? (u4 * c2 + u6 * s2) : (s2 * u0 + c2 * u4);
            const float p5 = r ? (u5 * c2 + u7 * s2) : (s2 * u1 + c2 * u5);
            const float p6 = r ? (u6 * c2 - u4 * s2) : (s2 * u2 + c2 * u6);
            const float p7 = r ? (u7 * c2 - u5 * s2) : (s2 * u3 + c2 * u7);
            u0 = p0; u1 = p1; u2 = p2; u3 = p3; u4 = p4; u5 = p5; u6 = p6; u7 = p7;
        }
        if (lane < 10) {
            *(float4*)&cs[lane * 8]     = (float4){u0, u2, u1, u3};
            *(float4*)&cs[lane * 8 + 4] = (float4){u4, u6, u5, u7};
        } else if (lane < 20) {
            const int qq = lane - 10;
            *(float4*)&cs[100 + qq * 8]     = (float4){u0, u1, u2, u3};
            *(float4*)&cs[100 + qq * 8 + 4] = (float4){u4, u5, u6, u7};
            if (qq == 0) {
                *(float4*)&cs[260] = (float4){u0, u1, u2, u3};
                *(float4*)&cs[264] = (float4){u4, u5, u6, u7};
            } else if (qq == 4) {
                *(float4*)&cs[356] = (float4){u0, u1, u2, u3};
                *(float4*)&cs[364] = (float4){u4, u5, u6, u7};
            } else if (qq >= 5) {
                const int g = qq - 5;
                if (g == 0) {
                    *(float4*)&cs[276 + 0] = (float4){u0, u1, u2, u3};
                    *(float4*)&cs[276 + 4] = (float4){u4, u5, u6, u7};
                } else {
                    *(float4*)&cs[276 + 16 * g + 0] = (float4){u0, u1, u2, u3};
                    *(float4*)&cs[276 + 16 * g + 4] = (float4){u6, u7, u4, u5};
                }
            }
        } else if (lane < 30) {
            const int off = (lane < 29) ? 80 + 2 * (lane - 20) : 98;
            *(float2*)&cs[off] = (float2){c2, s2};
            if (lane >= 24 && lane < 29) {
                const int g = lane - 24;
                float2 v0, v1, v2, v3;
                if (g == 0) { v0 = (float2){1.f, 0.f}; v1 = (float2){0.f, 1.f};
                              v2 = (float2){c2, -s2};  v3 = (float2){s2, c2}; }
                else        { v0 = (float2){1.f, 0.f}; v1 = (float2){1.f, 0.f};
                              v2 = (float2){c2, -s2};  v3 = (float2){c2, s2}; }
                *(float2*)&cs[372 + 8 * g + 0] = v0;
                *(float2*)&cs[372 + 8 * g + 2] = v1;
                *(float2*)&cs[372 + 8 * g + 4] = v2;
                *(float2*)&cs[372 + 8 * g + 6] = v3;
            }
        } else if (lane >= 40 && lane < 50) {
            *(float4*)&cs[180 + q * 8]     = (float4){u0, u1, u2, u3};
            *(float4*)&cs[180 + q * 8 + 4] = (float4){u4, u5, u6, u7};
            if (q == 0) {
                *(float4*)&cs[268] = (float4){u0, u1, u2, u3};
                *(float4*)&cs[272] = (float4){u4, u5, u6, u7};
            } else if (q == 4) {
                *(float4*)&cs[360] = (float4){u0, u1, u2, u3};
                *(float4*)&cs[368] = (float4){u4, u5, u6, u7};
            } else if (q >= 5) {
                const int g = q - 5;
                if (g == 0) {
                    *(float4*)&cs[276 + 8]  = (float4){u0, u1, u2, u3};
                    *(float4*)&cs[276 + 12] = (float4){u4, u5, u6, u7};
                } else {
                    *(float4*)&cs[276 + 16 * g + 8]  = (float4){u0, u1, u2, u3};
                    *(float4*)&cs[276 + 16 * g + 12] = (float4){u6, u7, u4, u5};
                }
            }
        }
    }
    __syncthreads();
    if (b >= B) return;

    // ---- distributed input fold (fp32) ----
    if (lane < 40) {
        const int q = lane >> 2;
        float x = in[b * NQ + q];
        x = fminf(fmaxf(x, 0.0f), 1.0f);
        const float a = 0.5f * 3.14159265358979323846f * x;
        const float ca = __cosf(a), sa = __sinf(a);
        const float M0 = cs[lane * 2], M1 = cs[lane * 2 + 1];
        tsh[wave * 40 + lane] = M0 * ca + M1 * sa;
    }
    const int base = wave * 40;

    float wr, wi;
    {
        const int bit = lane & 1;
        const float2 v = *(const float2*)&tsh[base + 9 * 4 + (bit << 1)];
        wr = v.x; wi = v.y;
    }
#pragma unroll
    for (int j = 1; j < 6; ++j) {
        const int bit = (lane >> j) & 1;
        const float2 v = *(const float2*)&tsh[base + (9 - j) * 4 + (bit << 1)];
        cmul(wr, wi, v.x, v.y);
    }
    const float4 T0 = *(const float4*)&tsh[base + 0];
    const float4 T1 = *(const float4*)&tsh[base + 4];
    const float4 T2 = *(const float4*)&tsh[base + 8];
    const float4 T3 = *(const float4*)&tsh[base + 12];

    float vrk[4], vik[4];
    { float r = T1.x, i2 = T1.y; vrk[0] = r * T2.x - i2 * T2.y; vik[0] = r * T2.y + i2 * T2.x;
                                  vrk[1] = r * T2.z - i2 * T2.w; vik[1] = r * T2.w + i2 * T2.z; }
    { float r = T1.z, i2 = T1.w; vrk[2] = r * T2.x - i2 * T2.y; vik[2] = r * T2.y + i2 * T2.x;
                                  vrk[3] = r * T2.z - i2 * T2.w; vik[3] = r * T2.w + i2 * T2.z; }
    h2 Sr[8], Si[8];
#pragma unroll
    for (int k = 0; k < 8; ++k) {
        const int hv = k >> 1;
        const float t3r = (k & 1) ? T3.z : T3.x;
        const float t3i = (k & 1) ? T3.w : T3.y;
        float kr = vrk[hv] * t3r - vik[hv] * t3i;
        float ki = vrk[hv] * t3i + vik[hv] * t3r;
        cmul(kr, ki, wr, wi);
        // Sr = kr*T0r - ki*T0i ; Si = kr*T0i + ki*T0r, T0r={T0.x,T0.z}, T0i={T0.y,T0.w}
        Sr[k] = (h2){H(kr * T0.x - ki * T0.y), H(kr * T0.z - ki * T0.w)};
        Si[k] = (h2){H(kr * T0.y + ki * T0.x), H(kr * T0.w + ki * T0.z)};
    }

    // ===== CRY_0 ring, e = 0..8 =====
    {   // e0: ctrl q0 (comp), tgt q1 (k bit2)
        const float2 C = *(const float2*)&cs[80];
        const h2 cv = {H(1.0f), H(C.x)};
        const h2 sv = {H(0.0f), H(C.y)};
#pragma unroll
        for (int k0 = 0; k0 < 4; ++k0) {
            const int k1 = k0 | 4;
            h2 n0r = cv * Sr[k0] - sv * Sr[k1];
            h2 n0i = cv * Si[k0] - sv * Si[k1];
            h2 n1r = sv * Sr[k0] + cv * Sr[k1];
            h2 n1i = sv * Si[k0] + cv * Si[k1];
            Sr[k0] = n0r; Si[k0] = n0i; Sr[k1] = n1r; Si[k1] = n1i;
        }
    }
    {   // e1: ctrl q1 (k bit2), tgt q2 (k bit1)
        const float2 C = *(const float2*)&cs[82];
        const _Float16 c = H(C.x), s = H(C.y);
        ry_pair_h(Sr[4], Si[4], Sr[6], Si[6], c, s);
        ry_pair_h(Sr[5], Si[5], Sr[7], Si[7], c, s);
    }
    {   // e2: ctrl q2 (k bit1), tgt q3 (k bit0)
        const float2 C = *(const float2*)&cs[84];
        const _Float16 c = H(C.x), s = H(C.y);
        ry_pair_h(Sr[2], Si[2], Sr[3], Si[3], c, s);
        ry_pair_h(Sr[6], Si[6], Sr[7], Si[7], c, s);
    }
    {   // e3: ctrl q3 (k bit0) -> odd k only; tgt q4 (lane bit5)
        const float2 C = *(const float2*)&cs[86];
        const bool hi = (lane >> 5) & 1;
        const _Float16 e = hi ? H(C.y) : H(C.x);
        const _Float16 f = hi ? H(C.x) : H(-C.y);
#pragma unroll
        for (int k = 1; k < 8; k += 2) {
            const HPair R = blkswap_h<5>(Sr[k], lane);
            const HPair I = blkswap_h<5>(Si[k], lane);
            Sr[k] = e * R.v0 + f * R.v1;
            Si[k] = e * I.v0 + f * I.v1;
        }
    }
    {   // e4: ctrl bit5, tgt bit4 — table fetch
        const int idx = (((lane >> 5) & 1) << 1) | ((lane >> 4) & 1);
        const float2 ef = *(const float2*)&cs[372 + idx * 2];
        gate_blk_real_h<4>(Sr, Si, lane, H(ef.x), H(ef.y));
    }
    {   // e5: ctrl bit4, tgt bit3
        const int idx = (((lane >> 4) & 1) << 1) | ((lane >> 3) & 1);
        const float2 cv = *(const float2*)&cs[380 + idx * 2];
        gate_dpp_real_h<3>(Sr, Si, H(cv.x), H(cv.y));
    }
    {   // e6: ctrl bit3, tgt bit2
        const int idx = (((lane >> 3) & 1) << 1) | ((lane >> 2) & 1);
        const float2 cv = *(const float2*)&cs[388 + idx * 2];
        gate_dpp_real_h<2>(Sr, Si, H(cv.x), H(cv.y));
    }
    {   // e7: ctrl bit2, tgt bit1
        const int idx = (((lane >> 2) & 1) << 1) | ((lane >> 1) & 1);
        const float2 cv = *(const float2*)&cs[396 + idx * 2];
        gate_dpp_real_h<1>(Sr, Si, H(cv.x), H(cv.y));
    }
    {   // e8: ctrl bit1, tgt bit0
        const int idx = (((lane >> 1) & 1) << 1) | (lane & 1);
        const float2 cv = *(const float2*)&cs[404 + idx * 2];
        gate_dpp_real_h<0>(Sr, Si, H(cv.x), H(cv.y));
    }

    // ===== F0 = U3_1(0) * CRY_0(9): ctrl q9 (lane bit0), tgt q0 (comp) =====
    {
        const int ctrl = lane & 1;
        const float4 ma = *(const float4*)&cs[260 + ctrl * 8];
        const float4 mb = *(const float4*)&cs[264 + ctrl * 8];
        const h2 Dr = {H(ma.x), H(mb.z)}, Di = {H(ma.y), H(mb.w)};
        const h2 Or = {H(ma.z), H(mb.x)}, Oi = {H(ma.w), H(mb.y)};
#pragma unroll
        for (int k = 0; k < 8; ++k) {
            const h2 Ar = Sr[k], Ai = Si[k];
            const h2 Br = Ar.yx, Bi = Ai.yx;
            Sr[k] = Dr * Ar - Di * Ai + Or * Br - Oi * Bi;
            Si[k] = Dr * Ai + Di * Ar + Or * Bi + Oi * Br;
        }
    }
    // ===== F1 = CRY_1(0) * U3_1(1): ctrl q0 (comp), tgt q1 (k bit2) =====
    {
        LOADM(A, 108); LOADM(Bm, 188);
        const h2 u00r = {H(A00r), H(Bm00r)}, u00i = {H(A00i), H(Bm00i)};
        const h2 u01r = {H(A01r), H(Bm01r)}, u01i = {H(A01i), H(Bm01i)};
        const h2 u10r = {H(A10r), H(Bm10r)}, u10i = {H(A10i), H(Bm10i)};
        const h2 u11r = {H(A11r), H(Bm11r)}, u11i = {H(A11i), H(Bm11i)};
#pragma unroll
        for (int k0 = 0; k0 < 4; ++k0) {
            const int k1 = k0 | 4;
            h2 n0r = u00r * Sr[k0] - u00i * Si[k0] + u01r * Sr[k1] - u01i * Si[k1];
            h2 n0i = u00r * Si[k0] + u00i * Sr[k0] + u01r * Si[k1] + u01i * Sr[k1];
            h2 n1r = u10r * Sr[k0] - u10i * Si[k0] + u11r * Sr[k1] - u11i * Si[k1];
            h2 n1i = u10r * Si[k0] + u10i * Sr[k0] + u11r * Si[k1] + u11i * Sr[k1];
            Sr[k0] = n0r; Si[k0] = n0i; Sr[k1] = n1r; Si[k1] = n1i;
        }
    }
    // ===== F2 = CRY_1(1) * U3_1(2): ctrl q1 (k bit2), tgt q2 (k bit1) =====
    {
        LOADM(A, 116); LOADM(Bm, 196);
        u3_pair_h(Sr[0], Si[0], Sr[2], Si[2], H(A00r), H(A00i), H(A01r), H(A01i), H(A10r), H(A10i), H(A11r), H(A11i));
        u3_pair_h(Sr[1], Si[1], Sr[3], Si[3], H(A00r), H(A00i), H(A01r), H(A01i), H(A10r), H(A10i), H(A11r), H(A11i));
        u3_pair_h(Sr[4], Si[4], Sr[6], Si[6], H(Bm00r), H(Bm00i), H(Bm01r), H(Bm01i), H(Bm10r), H(Bm10i), H(Bm11r), H(Bm11i));
        u3_pair_h(Sr[5], Si[5], Sr[7], Si[7], H(Bm00r), H(Bm00i), H(Bm01r), H(Bm01i), H(Bm10r), H(Bm10i), H(Bm11r), H(Bm11i));
    }
    // ===== F3 = CRY_1(2) * U3_1(3): ctrl q2 (k bit1), tgt q3 (k bit0) =====
    {
        LOADM(A, 124); LOADM(Bm, 204);
        u3_pair_h(Sr[0], Si[0], Sr[1], Si[1], H(A00r), H(A00i), H(A01r), H(A01i), H(A10r), H(A10i), H(A11r), H(A11i));
        u3_pair_h(Sr[4], Si[4], Sr[5], Si[5], H(A00r), H(A00i), H(A01r), H(A01i), H(A10r), H(A10i), H(A11r), H(A11i));
        u3_pair_h(Sr[2], Si[2], Sr[3], Si[3], H(Bm00r), H(Bm00i), H(Bm01r), H(Bm01i), H(Bm10r), H(Bm10i), H(Bm11r), H(Bm11i));
        u3_pair_h(Sr[6], Si[6], Sr[7], Si[7], H(Bm00r), H(Bm00i), H(Bm01r), H(Bm01i), H(Bm10r), H(Bm10i), H(Bm11r), H(Bm11i));
    }
    // ===== F4 = CRY_1(3) * U3_1(4): ctrl q3 (k bit0), tgt q4 (lane bit5) =====
    {
        const int hi = (lane >> 5) & 1;
        const float4 ra = *(const float4*)&cs[356 + hi * 8];
        const float4 rb = *(const float4*)&cs[360 + hi * 8];
        const _Float16 eAr = H(ra.x), eAi = H(ra.y), fAr = H(ra.z), fAi = H(ra.w);
        const _Float16 eBr = H(rb.x), eBi = H(rb.y), fBr = H(rb.z), fBi = H(rb.w);
#pragma unroll
        for (int k = 0; k < 8; ++k) {
            const _Float16 er = (k & 1) ? eBr : eAr, ei = (k & 1) ? eBi : eAi;
            const _Float16 fr = (k & 1) ? fBr : fAr, fi = (k & 1) ? fBi : fAi;
            const HPair R = blkswap_h<5>(Sr[k], lane);
            const HPair I = blkswap_h<5>(Si[k], lane);
            Sr[k] = er * R.v0 - ei * I.v0 + fr * R.v1 - fi * I.v1;
            Si[k] = er * I.v0 + ei * R.v0 + fr * I.v1 + fi * R.v1;
        }
    }
    // ===== F5: ctrl bit5, tgt bit4 — table fetch =====
    {
        const int idx = (((lane >> 5) & 1) << 1) | ((lane >> 4) & 1);
        const float4 r = *(const float4*)&cs[276 + idx * 4];
        gate_blk_full_h<4>(Sr, Si, lane, H(r.x), H(r.y), H(r.z), H(r.w));
    }
    // ===== F6..F9: DPP lane-bit gates — table fetch =====
    {
        const int idx = (((lane >> 4) & 1) << 1) | ((lane >> 3) & 1);
        const float4 r = *(const float4*)&cs[292 + idx * 4];
        gate_dpp_full_h<3>(Sr, Si, H(r.x), H(r.y), H(r.z), H(r.w));
    }
    {
        const int idx = (((lane >> 3) & 1) << 1) | ((lane >> 2) & 1);
        const float4 r = *(const float4*)&cs[308 + idx * 4];
        gate_dpp_full_h<2>(Sr, Si, H(r.x), H(r.y), H(r.z), H(r.w));
    }
    {
        const int idx = (((lane >> 2) & 1) << 1) | ((lane >> 1) & 1);
        const float4 r = *(const float4*)&cs[324 + idx * 4];
        gate_dpp_full_h<1>(Sr, Si, H(r.x), H(r.y), H(r.z), H(r.w));
    }
    {
        const int idx = (((lane >> 1) & 1) << 1) | (lane & 1);
        const float4 r = *(const float4*)&cs[340 + idx * 4];
        gate_dpp_full_h<0>(Sr, Si, H(r.x), H(r.y), H(r.z), H(r.w));
    }
    // ===== CRY_1(9): ctrl q9 (lane bit0), tgt q0 (comp) =====
    {
        const float2 C = *(const float2*)&cs[98];
        const bool ctrl = lane & 1;
        const float cl = ctrl ? C.x : 1.0f;
        const float sl = ctrl ? C.y : 0.0f;
        const h2 C2 = {H(cl), H(cl)};
        const h2 S2 = {H(-sl), H(sl)};
#pragma unroll
        for (int k = 0; k < 8; ++k) {
            const h2 Ar = Sr[k], Ai = Si[k];
            Sr[k] = C2 * Ar + S2 * Ar.yx;
            Si[k] = C2 * Ai + S2 * Ai.yx;
        }
    }

    // ===== measurement (fp32) =====
    v2f P[8];
    float ptot = 0.0f, z0p = 0.0f, z1p = 0.0f, z2p = 0.0f, z3p = 0.0f;
#pragma unroll
    for (int k = 0; k < 8; ++k) {
        const float arx = (float)Sr[k].x, ary = (float)Sr[k].y;
        const float aix = (float)Si[k].x, aiy = (float)Si[k].y;
        P[k].x = arx * arx + aix * aix;
        P[k].y = ary * ary + aiy * aiy;
        const float sk = P[k].x + P[k].y;
        ptot += sk;
        z0p += P[k].x - P[k].y;
        z1p += ((k >> 2) & 1) ? -sk : sk;
        z2p += ((k >> 1) & 1) ? -sk : sk;
        z3p += (k & 1) ? -sk : sk;
    }
    float d0, d1, d2, d3, d4, d5;
    {
        float a = ptot, p;
        p = partner1<0>(a); d0 = a - p; a += p;
        p = partner1<1>(a); d1 = a - p; a += p;
        p = partner1<2>(a); d2 = a - p; a += p;
        p = partner1<3>(a); d3 = a - p; a += p;
        { const FPair o = blkswap1<4>(a, lane); d4 = o.v0 - o.v1; a = o.v0 + o.v1; }
        { const FPair o = blkswap1<5>(a, lane); d5 = o.v0 - o.v1; }
    }
    const v2f z01 = vplus_reduce((v2f){z0p, z1p}, lane);
    const v2f z23 = vplus_reduce((v2f){z2p, z3p}, lane);
    float z[NQ];
    z[0] = z01.x; z[1] = z01.y; z[2] = z23.x; z[3] = z23.y;
    z[4] = d5;
    z[5] = plus_reduce<5>(d4, lane);
    z[6] = plus_reduce<4>(d3, lane);
    z[7] = plus_reduce<3>(d2, lane);
    z[8] = plus_reduce<2>(d1, lane);
    z[9] = plus_reduce<1>(d0, lane);

    if (lane == 0) {
#pragma unroll
        for (int q = 0; q < NQ; ++q) out[b * NQ + q] = z[q];
    }
}

extern "C" void kernel_launch(void* const* d_in, const int* in_sizes, int n_in,
                              void* d_out, int out_size, void* d_ws, size_t ws_size,
                              hipStream_t stream) {
    const float* inputs  = (const float*)d_in[0];
    const float* weights = (const float*)d_in[1];
    float* out = (float*)d_out;
    const int B = in_sizes[0] / NQ;

    qsim<<<(B + 3) / 4, 256, 0, stream>>>(inputs, weights, out, B);
}

// Round 13
// 80.150 us; speedup vs baseline: 1.0551x; 1.0100x over previous
//
#include <hip/hip_runtime.h>
#include <math.h>

#define NQ 10
typedef float v2f __attribute__((ext_vector_type(2)));
typedef _Float16 h2 __attribute__((ext_vector_type(2)));
#define H(x) ((_Float16)(x))

#if defined(__has_builtin)
#if __has_builtin(__builtin_amdgcn_permlane16_swap) && __has_builtin(__builtin_amdgcn_permlane32_swap)
#define HAVE_PL 1
#endif
#if __has_builtin(__builtin_amdgcn_fdot2)
#define HAVE_FDOT2 1
#endif
#endif

__device__ __forceinline__ int h2i(h2 v) { return __builtin_bit_cast(int, v); }
__device__ __forceinline__ h2 ih2(int v) { return __builtin_bit_cast(h2, v); }

template<int CTRL>
__device__ __forceinline__ float dppf(float x) {
    return __int_as_float(__builtin_amdgcn_update_dpp(
        __float_as_int(x), __float_as_int(x), CTRL, 0xF, 0xF, true));
}
template<int CTRL>
__device__ __forceinline__ h2 dpph(h2 x) {
    return ih2(__builtin_amdgcn_update_dpp(h2i(x), h2i(x), CTRL, 0xF, 0xF, true));
}
template<int OFS>
__device__ __forceinline__ float swzf(float x) {
    return __int_as_float(__builtin_amdgcn_ds_swizzle(__float_as_int(x), OFS));
}
__device__ __forceinline__ float bperm(int idx, float x) {
    return __int_as_float(__builtin_amdgcn_ds_bpermute(idx, __float_as_int(x)));
}

// fp32 partner (measurement only)
template<int P>
__device__ __forceinline__ float partner1(float x) {
    if constexpr (P == 0) return dppf<0xB1>(x);
    else if constexpr (P == 1) return dppf<0x4E>(x);
    else if constexpr (P == 2) return dppf<0x1B>(dppf<0x141>(x));
    else return dppf<0x128>(x);
}
template<int P>
__device__ __forceinline__ v2f partner2(v2f v) {
    v2f r; r.x = partner1<P>(v.x); r.y = partner1<P>(v.y); return r;
}
// h2 partner: one DPP moves both components
template<int P>
__device__ __forceinline__ h2 partner_h(h2 x) {
    if constexpr (P == 0) return dpph<0xB1>(x);
    else if constexpr (P == 1) return dpph<0x4E>(x);
    else if constexpr (P == 2) return dpph<0x1B>(dpph<0x141>(x));
    else return dpph<0x128>(x);
}

// fp32 block swap (measurement)
struct FPair { float v0, v1; };
template<int P>
__device__ __forceinline__ FPair blkswap1(float x, int lane) {
    FPair o;
#ifdef HAVE_PL
    if constexpr (P == 4) {
        auto r = __builtin_amdgcn_permlane16_swap(__float_as_uint(x), __float_as_uint(x), false, false);
        o.v0 = __uint_as_float(r[0]);
        o.v1 = __uint_as_float(r[1]);
    } else {
        auto r = __builtin_amdgcn_permlane32_swap(__float_as_uint(x), __float_as_uint(x), false, false);
        o.v0 = __uint_as_float(r[0]);
        o.v1 = __uint_as_float(r[1]);
    }
#else
    const float p = (P == 4) ? swzf<0x401F>(x) : bperm((lane ^ 32) << 2, x);
    const bool hi = (lane >> P) & 1;
    o.v0 = hi ? p : x;
    o.v1 = hi ? x : p;
#endif
    return o;
}
struct VPair { v2f V0, V1; };
template<int P>
__device__ __forceinline__ VPair blkswap2(v2f x, int lane) {
    const FPair a = blkswap1<P>(x.x, lane);
    const FPair b = blkswap1<P>(x.y, lane);
    VPair o;
    o.V0 = (v2f){a.v0, b.v0};
    o.V1 = (v2f){a.v1, b.v1};
    return o;
}
template<int P>
__device__ __forceinline__ float blkadd(float x, int lane) {
    const FPair o = blkswap1<P>(x, lane);
    return o.v0 + o.v1;
}
// h2 block swap
struct HPair { h2 v0, v1; };
template<int P>
__device__ __forceinline__ HPair blkswap_h(h2 x, int lane) {
    HPair o;
#ifdef HAVE_PL
    if constexpr (P == 4) {
        auto r = __builtin_amdgcn_permlane16_swap((unsigned)h2i(x), (unsigned)h2i(x), false, false);
        o.v0 = ih2((int)r[0]);
        o.v1 = ih2((int)r[1]);
    } else {
        auto r = __builtin_amdgcn_permlane32_swap((unsigned)h2i(x), (unsigned)h2i(x), false, false);
        o.v0 = ih2((int)r[0]);
        o.v1 = ih2((int)r[1]);
    }
#else
    const int pv = (P == 4) ? __builtin_amdgcn_ds_swizzle(h2i(x), 0x401F)
                            : __builtin_amdgcn_ds_bpermute((lane ^ 32) << 2, h2i(x));
    const h2 p = ih2(pv);
    const bool hi = (lane >> P) & 1;
    o.v0 = hi ? p : x;
    o.v1 = hi ? x : p;
#endif
    return o;
}

// ---- aligned multi-h2 LDS loads ----
struct H2x2 { h2 a, b; };
__device__ __forceinline__ H2x2 ld2(const h2* p) {
    const float2 v = *(const float2*)p;
    H2x2 o;
    o.a = __builtin_bit_cast(h2, v.x);
    o.b = __builtin_bit_cast(h2, v.y);
    return o;
}
struct H2x4 { h2 a, b, c, d; };
__device__ __forceinline__ H2x4 ld4(const h2* p) {
    const float4 v = *(const float4*)p;
    H2x4 o;
    o.a = __builtin_bit_cast(h2, v.x);
    o.b = __builtin_bit_cast(h2, v.y);
    o.c = __builtin_bit_cast(h2, v.z);
    o.d = __builtin_bit_cast(h2, v.w);
    return o;
}

// ---- h2-coefficient gate bodies (all operands h2 -> guaranteed v_pk_*_f16) ----
template<int P>
__device__ __forceinline__ void gate_blk_full_h2(h2 (&Sr)[8], h2 (&Si)[8], int lane,
                                                 h2 er, h2 ei, h2 fr, h2 fi) {
#pragma unroll
    for (int k = 0; k < 8; ++k) {
        const HPair R = blkswap_h<P>(Sr[k], lane);
        const HPair I = blkswap_h<P>(Si[k], lane);
        Sr[k] = er * R.v0 - ei * I.v0 + fr * R.v1 - fi * I.v1;
        Si[k] = er * I.v0 + ei * R.v0 + fr * I.v1 + fi * R.v1;
    }
}
template<int P>
__device__ __forceinline__ void gate_blk_real_h2(h2 (&Sr)[8], h2 (&Si)[8], int lane,
                                                 h2 e, h2 f) {
#pragma unroll
    for (int k = 0; k < 8; ++k) {
        const HPair R = blkswap_h<P>(Sr[k], lane);
        const HPair I = blkswap_h<P>(Si[k], lane);
        Sr[k] = e * R.v0 + f * R.v1;
        Si[k] = e * I.v0 + f * I.v1;
    }
}
template<int P>
__device__ __forceinline__ void gate_dpp_full_h2(h2 (&Sr)[8], h2 (&Si)[8],
                                                 h2 dr, h2 di, h2 orr, h2 oii) {
#pragma unroll
    for (int k = 0; k < 8; ++k) {
        const h2 mr = Sr[k], mi = Si[k];
        const h2 pr = partner_h<P>(mr);
        const h2 pi = partner_h<P>(mi);
        Sr[k] = dr * mr - di * mi + orr * pr - oii * pi;
        Si[k] = dr * mi + di * mr + orr * pi + oii * pr;
    }
}
template<int P>
__device__ __forceinline__ void gate_dpp_real_h2(h2 (&Sr)[8], h2 (&Si)[8],
                                                 h2 cl, h2 sg) {
#pragma unroll
    for (int k = 0; k < 8; ++k) {
        const h2 pr = partner_h<P>(Sr[k]);
        const h2 pi = partner_h<P>(Si[k]);
        Sr[k] = cl * Sr[k] + sg * pr;
        Si[k] = cl * Si[k] + sg * pi;
    }
}
__device__ __forceinline__ void u3_pair_h2(h2& a0r, h2& a0i, h2& a1r, h2& a1i,
                                           h2 c00r, h2 c00i, h2 c01r, h2 c01i,
                                           h2 c10r, h2 c10i, h2 c11r, h2 c11i) {
    h2 n0r = c00r * a0r - c00i * a0i + c01r * a1r - c01i * a1i;
    h2 n0i = c00r * a0i + c00i * a0r + c01r * a1i + c01i * a1r;
    h2 n1r = c10r * a0r - c10i * a0i + c11r * a1r - c11i * a1i;
    h2 n1i = c10r * a0i + c10i * a0r + c11r * a1i + c11i * a1r;
    a0r = n0r; a0i = n0i; a1r = n1r; a1i = n1i;
}
__device__ __forceinline__ void ry_pair_h2(h2& a0r, h2& a0i, h2& a1r, h2& a1i,
                                           h2 C, h2 S) {
    h2 n0r = C * a0r - S * a1r;
    h2 n0i = C * a0i - S * a1i;
    h2 n1r = S * a0r + C * a1r;
    h2 n1i = S * a0i + C * a1i;
    a0r = n0r; a0i = n0i; a1r = n1r; a1i = n1i;
}
__device__ __forceinline__ void cmul(float& xr, float& xi, float br, float bi) {
    const float nr = xr * br - xi * bi;
    const float ni = xr * bi + xi * br;
    xr = nr; xi = ni;
}

template<int FROM>
__device__ __forceinline__ float plus_reduce(float x, int lane) {
    if constexpr (FROM <= 0) x += partner1<0>(x);
    if constexpr (FROM <= 1) x += partner1<1>(x);
    if constexpr (FROM <= 2) x += partner1<2>(x);
    if constexpr (FROM <= 3) x += partner1<3>(x);
    if constexpr (FROM <= 4) x = blkadd<4>(x, lane);
    x = blkadd<5>(x, lane);
    return x;
}
__device__ __forceinline__ v2f vplus_reduce(v2f x, int lane) {
    x += partner2<0>(x);
    x += partner2<1>(x);
    x += partner2<2>(x);
    x += partner2<3>(x);
    { const VPair o = blkswap2<4>(x, lane); x = o.V0 + o.V1; }
    { const VPair o = blkswap2<5>(x, lane); x = o.V0 + o.V1; }
    return x;
}

// hsh (h2-word indices; all gate coefficients pre-converted/pre-broadcast fp16):
//  0,1: e0 cv={1,c}, sv={0,s}
//  2,3: e1 {c,c},{s,s} ; 4,5: e2
//  6..9: e3 by hi: [6+2hi]={e,e},[7+2hi]={f,f}
//  10..13: CRY_1(9) by ctrl: C2,S2
//  16..55: e4..e8 (g): [16+8g+2*idx]={a,a}, +1={b,b}   idx=(ctrl<<1)|hi
//  56..63: F0 by ctrl: Dr,Di,Or,Oi (true 2-vectors)
//  64..71: F1: u00r,u00i,u01r,u01i,u10r,u10i,u11r,u11i  ({A,B} vectors)
//  72..87: F2 A (8 bcast) + B (8) ; 88..103: F3
//  104..119: F4: A-row(hi0)4, B-row(hi0)4, A-row(hi1)4, B-row(hi1)4 (bcast)
//  120..199: F5..F9 (g): [120+16g+4*idx ..+3] = (dr,di,or,oi)/(er,ei,fr,fi) bcast
__global__ __launch_bounds__(256) void qsim(const float* __restrict__ in,
                                            const float* __restrict__ w,
                                            float* __restrict__ out, int B) {
    __shared__ __attribute__((aligned(16))) float csh[80];      // U3_0 rows (fp32)
    __shared__ __attribute__((aligned(16))) float tsh[4 * 40];
    __shared__ __attribute__((aligned(16))) h2 hsh[200];
    const int lane = threadIdx.x & 63;
    const int wave = threadIdx.x >> 6;
    int b = blockIdx.x * 4 + wave;
    b = __builtin_amdgcn_readfirstlane(b);
    const float* cs = csh;

    // ===== coefficient generation: wave 0 only =====
    if (wave == 0) {
        const int q = (lane < 20) ? (lane % 10) : ((lane >= 40 && lane < 50) ? lane - 40 : 0);
        const int wb = (lane < 10) ? 3 * lane : 40 + 3 * q;
        const float phi = w[wb], theta = w[wb + 1], omega = w[wb + 2];
        float u0, u1, u2, u3, u4, u5, u6, u7;
        {
            const float ct = __cosf(0.5f * theta), st = __sinf(0.5f * theta);
            const float apo = 0.5f * (phi + omega), amo = 0.5f * (phi - omega);
            const float capo = __cosf(apo), sapo = __sinf(apo);
            const float camo = __cosf(amo), samo = __sinf(amo);
            u0 =  capo * ct;  u1 = -sapo * ct;   // U00
            u2 = -camo * st;  u3 = -samo * st;   // U01
            u4 =  camo * st;  u5 = -samo * st;   // U10
            u6 =  capo * ct;  u7 =  sapo * ct;   // U11
        }
        const int cidx = (lane >= 20 && lane < 29) ? 30 + (lane - 20)
                       : (lane == 29) ? 79
                       : (lane == 40) ? 39
                       : 70 + (q - 1) + (q == 0 ? 1 : 0);
        const float th = 0.5f * w[cidx];
        const float c2 = __cosf(th), s2 = __sinf(th);
        if (lane >= 40 && lane < 50) {           // fold RY -> B_q
            const bool r = (lane == 40);
            const float p0 = r ? (u0 * c2 + u2 * s2) : (c2 * u0 - s2 * u4);
            const float p1 = r ? (u1 * c2 + u3 * s2) : (c2 * u1 - s2 * u5);
            const float p2 = r ? (u2 * c2 - u0 * s2) : (c2 * u2 - s2 * u6);
            const float p3 = r ? (u3 * c2 - u1 * s2) : (c2 * u3 - s2 * u7);
            const float p4 = r ? (u4 * c2 + u6 * s2) : (s2 * u0 + c2 * u4);
            const float p5 = r ? (u5 * c2 + u7 * s2) : (s2 * u1 + c2 * u5);
            const float p6 = r ? (u6 * c2 - u4 * s2) : (s2 * u2 + c2 * u6);
            const float p7 = r ? (u7 * c2 - u5 * s2) : (s2 * u3 + c2 * u7);
            u0 = p0; u1 = p1; u2 = p2; u3 = p3; u4 = p4; u5 = p5; u6 = p6; u7 = p7;
        }
        const _Float16 uh0 = H(u0), uh1 = H(u1), uh2 = H(u2), uh3 = H(u3),
                       uh4 = H(u4), uh5 = H(u5), uh6 = H(u6), uh7 = H(u7);
        if (lane < 10) {                         // U3_0 rows (fp32, for input fold)
            *(float4*)&csh[lane * 8]     = (float4){u0, u2, u1, u3};
            *(float4*)&csh[lane * 8 + 4] = (float4){u4, u6, u5, u7};
        } else if (lane < 20 || (lane >= 40 && lane < 50)) {
            const bool isB = lane >= 40;
            if (q == 0) {                        // F0: Dr,Di,Or,Oi
                const int o = 56 + (isB ? 4 : 0);
                hsh[o + 0] = (h2){uh0, uh6};
                hsh[o + 1] = (h2){uh1, uh7};
                hsh[o + 2] = (h2){uh2, uh4};
                hsh[o + 3] = (h2){uh3, uh5};
            } else if (q == 1) {                 // F1 interleaved halves
                _Float16* p = (_Float16*)&hsh[64];
                const int off = isB ? 1 : 0;
                p[0 * 2 + off] = uh0; p[1 * 2 + off] = uh1;
                p[2 * 2 + off] = uh2; p[3 * 2 + off] = uh3;
                p[4 * 2 + off] = uh4; p[5 * 2 + off] = uh5;
                p[6 * 2 + off] = uh6; p[7 * 2 + off] = uh7;
            } else if (q == 2 || q == 3) {       // F2 / F3 broadcast
                const int o = (q == 2 ? 72 : 88) + (isB ? 8 : 0);
                hsh[o + 0] = (h2){uh0, uh0}; hsh[o + 1] = (h2){uh1, uh1};
                hsh[o + 2] = (h2){uh2, uh2}; hsh[o + 3] = (h2){uh3, uh3};
                hsh[o + 4] = (h2){uh4, uh4}; hsh[o + 5] = (h2){uh5, uh5};
                hsh[o + 6] = (h2){uh6, uh6}; hsh[o + 7] = (h2){uh7, uh7};
            } else if (q == 4) {                 // F4 rows by hi
                const int o = 104 + (isB ? 4 : 0);
                hsh[o + 0] = (h2){uh0, uh0}; hsh[o + 1] = (h2){uh1, uh1};
                hsh[o + 2] = (h2){uh2, uh2}; hsh[o + 3] = (h2){uh3, uh3};
                hsh[o + 8] = (h2){uh4, uh4}; hsh[o + 9] = (h2){uh5, uh5};
                hsh[o + 10] = (h2){uh6, uh6}; hsh[o + 11] = (h2){uh7, uh7};
            } else {                             // F5..F9 variants
                const int g = q - 5;
                const int o = 120 + g * 16 + (isB ? 8 : 0);
                hsh[o + 0] = (h2){uh0, uh0}; hsh[o + 1] = (h2){uh1, uh1};
                hsh[o + 2] = (h2){uh2, uh2}; hsh[o + 3] = (h2){uh3, uh3};
                if (g == 0) {                    // F5: natural row1
                    hsh[o + 4] = (h2){uh4, uh4}; hsh[o + 5] = (h2){uh5, uh5};
                    hsh[o + 6] = (h2){uh6, uh6}; hsh[o + 7] = (h2){uh7, uh7};
                } else {                         // F6-9: diag-first row1
                    hsh[o + 4] = (h2){uh6, uh6}; hsh[o + 5] = (h2){uh7, uh7};
                    hsh[o + 6] = (h2){uh4, uh4}; hsh[o + 7] = (h2){uh5, uh5};
                }
            }
        } else if (lane >= 20 && lane < 30) {
            const _Float16 fc = H(c2), fs = H(s2);
            if (lane == 20) {        // e0
                hsh[0] = (h2){H(1.0f), fc};
                hsh[1] = (h2){H(0.0f), fs};
            } else if (lane == 21) { // e1
                hsh[2] = (h2){fc, fc}; hsh[3] = (h2){fs, fs};
            } else if (lane == 22) { // e2
                hsh[4] = (h2){fc, fc}; hsh[5] = (h2){fs, fs};
            } else if (lane == 23) { // e3 by hi
                hsh[6] = (h2){fc, fc};   hsh[7] = (h2){-fs, -fs};
                hsh[8] = (h2){fs, fs};   hsh[9] = (h2){fc, fc};
            } else if (lane == 29) { // CRY_1(9) by ctrl
                hsh[10] = (h2){H(1.0f), H(1.0f)}; hsh[11] = (h2){H(0.0f), H(0.0f)};
                hsh[12] = (h2){fc, fc};           hsh[13] = (h2){-fs, fs};
            } else {                 // lanes 24..28 -> e4..e8
                const int g = lane - 24;
                const int o = 16 + g * 8;
                if (g == 0) {
                    hsh[o + 0] = (h2){H(1.0f), H(1.0f)}; hsh[o + 1] = (h2){H(0.0f), H(0.0f)};
                    hsh[o + 2] = (h2){H(0.0f), H(0.0f)}; hsh[o + 3] = (h2){H(1.0f), H(1.0f)};
                    hsh[o + 4] = (h2){fc, fc};           hsh[o + 5] = (h2){-fs, -fs};
                    hsh[o + 6] = (h2){fs, fs};           hsh[o + 7] = (h2){fc, fc};
                } else {
                    hsh[o + 0] = (h2){H(1.0f), H(1.0f)}; hsh[o + 1] = (h2){H(0.0f), H(0.0f)};
                    hsh[o + 2] = (h2){H(1.0f), H(1.0f)}; hsh[o + 3] = (h2){H(0.0f), H(0.0f)};
                    hsh[o + 4] = (h2){fc, fc};           hsh[o + 5] = (h2){-fs, -fs};
                    hsh[o + 6] = (h2){fc, fc};           hsh[o + 7] = (h2){fs, fs};
                }
            }
        }
    }
    __syncthreads();
    if (b >= B) return;

    // ---- distributed input fold (fp32) ----
    if (lane < 40) {
        const int q = lane >> 2;
        float x = in[b * NQ + q];
        x = fminf(fmaxf(x, 0.0f), 1.0f);
        const float a = 0.5f * 3.14159265358979323846f * x;
        const float ca = __cosf(a), sa = __sinf(a);
        const float M0 = cs[lane * 2], M1 = cs[lane * 2 + 1];
        tsh[wave * 40 + lane] = M0 * ca + M1 * sa;
    }
    const int base = wave * 40;

    float wr, wi;
    {
        const int bit = lane & 1;
        const float2 v = *(const float2*)&tsh[base + 9 * 4 + (bit << 1)];
        wr = v.x; wi = v.y;
    }
#pragma unroll
    for (int j = 1; j < 6; ++j) {
        const int bit = (lane >> j) & 1;
        const float2 v = *(const float2*)&tsh[base + (9 - j) * 4 + (bit << 1)];
        cmul(wr, wi, v.x, v.y);
    }
    const float4 T0 = *(const float4*)&tsh[base + 0];
    const float4 T1 = *(const float4*)&tsh[base + 4];
    const float4 T2 = *(const float4*)&tsh[base + 8];
    const float4 T3 = *(const float4*)&tsh[base + 12];

    float vrk[4], vik[4];
    { float r = T1.x, i2 = T1.y; vrk[0] = r * T2.x - i2 * T2.y; vik[0] = r * T2.y + i2 * T2.x;
                                  vrk[1] = r * T2.z - i2 * T2.w; vik[1] = r * T2.w + i2 * T2.z; }
    { float r = T1.z, i2 = T1.w; vrk[2] = r * T2.x - i2 * T2.y; vik[2] = r * T2.y + i2 * T2.x;
                                  vrk[3] = r * T2.z - i2 * T2.w; vik[3] = r * T2.w + i2 * T2.z; }
    h2 Sr[8], Si[8];
#pragma unroll
    for (int k = 0; k < 8; ++k) {
        const int hv = k >> 1;
        const float t3r = (k & 1) ? T3.z : T3.x;
        const float t3i = (k & 1) ? T3.w : T3.y;
        float kr = vrk[hv] * t3r - vik[hv] * t3i;
        float ki = vrk[hv] * t3i + vik[hv] * t3r;
        cmul(kr, ki, wr, wi);
        Sr[k] = (h2){H(kr * T0.x - ki * T0.y), H(kr * T0.z - ki * T0.w)};
        Si[k] = (h2){H(kr * T0.y + ki * T0.x), H(kr * T0.w + ki * T0.z)};
    }

    // ===== CRY_0 ring =====
    {   // e0: ctrl q0 (comp), tgt q1 (k bit2)
        const H2x2 C = ld2(&hsh[0]);
        const h2 cv = C.a, sv = C.b;
#pragma unroll
        for (int k0 = 0; k0 < 4; ++k0) {
            const int k1 = k0 | 4;
            h2 n0r = cv * Sr[k0] - sv * Sr[k1];
            h2 n0i = cv * Si[k0] - sv * Si[k1];
            h2 n1r = sv * Sr[k0] + cv * Sr[k1];
            h2 n1i = sv * Si[k0] + cv * Si[k1];
            Sr[k0] = n0r; Si[k0] = n0i; Sr[k1] = n1r; Si[k1] = n1i;
        }
    }
    {   // e1
        const H2x2 C = ld2(&hsh[2]);
        ry_pair_h2(Sr[4], Si[4], Sr[6], Si[6], C.a, C.b);
        ry_pair_h2(Sr[5], Si[5], Sr[7], Si[7], C.a, C.b);
    }
    {   // e2
        const H2x2 C = ld2(&hsh[4]);
        ry_pair_h2(Sr[2], Si[2], Sr[3], Si[3], C.a, C.b);
        ry_pair_h2(Sr[6], Si[6], Sr[7], Si[7], C.a, C.b);
    }
    {   // e3: odd k only; tgt lane bit5
        const int hi = (lane >> 5) & 1;
        const H2x2 C = ld2(&hsh[6 + hi * 2]);
#pragma unroll
        for (int k = 1; k < 8; k += 2) {
            const HPair R = blkswap_h<5>(Sr[k], lane);
            const HPair I = blkswap_h<5>(Si[k], lane);
            Sr[k] = C.a * R.v0 + C.b * R.v1;
            Si[k] = C.a * I.v0 + C.b * I.v1;
        }
    }
    {   // e4: ctrl bit5, tgt bit4
        const int idx = (((lane >> 5) & 1) << 1) | ((lane >> 4) & 1);
        const H2x2 C = ld2(&hsh[16 + idx * 2]);
        gate_blk_real_h2<4>(Sr, Si, lane, C.a, C.b);
    }
    {   // e5: ctrl bit4, tgt bit3
        const int idx = (((lane >> 4) & 1) << 1) | ((lane >> 3) & 1);
        const H2x2 C = ld2(&hsh[24 + idx * 2]);
        gate_dpp_real_h2<3>(Sr, Si, C.a, C.b);
    }
    {   // e6: ctrl bit3, tgt bit2
        const int idx = (((lane >> 3) & 1) << 1) | ((lane >> 2) & 1);
        const H2x2 C = ld2(&hsh[32 + idx * 2]);
        gate_dpp_real_h2<2>(Sr, Si, C.a, C.b);
    }
    {   // e7: ctrl bit2, tgt bit1
        const int idx = (((lane >> 2) & 1) << 1) | ((lane >> 1) & 1);
        const H2x2 C = ld2(&hsh[40 + idx * 2]);
        gate_dpp_real_h2<1>(Sr, Si, C.a, C.b);
    }
    {   // e8: ctrl bit1, tgt bit0
        const int idx = (((lane >> 1) & 1) << 1) | (lane & 1);
        const H2x2 C = ld2(&hsh[48 + idx * 2]);
        gate_dpp_real_h2<0>(Sr, Si, C.a, C.b);
    }

    // ===== F0: ctrl q9 (lane bit0), tgt q0 (comp) =====
    {
        const int ctrl = lane & 1;
        const H2x4 M = ld4(&hsh[56 + ctrl * 4]);   // Dr,Di,Or,Oi
#pragma unroll
        for (int k = 0; k < 8; ++k) {
            const h2 Ar = Sr[k], Ai = Si[k];
            const h2 Br = Ar.yx, Bi = Ai.yx;
            Sr[k] = M.a * Ar - M.b * Ai + M.c * Br - M.d * Bi;
            Si[k] = M.a * Ai + M.b * Ar + M.c * Bi + M.d * Br;
        }
    }
    // ===== F1: ctrl q0 (comp), tgt q1 (k bit2) =====
    {
        const H2x4 Ua = ld4(&hsh[64]);   // u00r,u00i,u01r,u01i
        const H2x4 Ub = ld4(&hsh[68]);   // u10r,u10i,u11r,u11i
#pragma unroll
        for (int k0 = 0; k0 < 4; ++k0) {
            const int k1 = k0 | 4;
            h2 n0r = Ua.a * Sr[k0] - Ua.b * Si[k0] + Ua.c * Sr[k1] - Ua.d * Si[k1];
            h2 n0i = Ua.a * Si[k0] + Ua.b * Sr[k0] + Ua.c * Si[k1] + Ua.d * Sr[k1];
            h2 n1r = Ub.a * Sr[k0] - Ub.b * Si[k0] + Ub.c * Sr[k1] - Ub.d * Si[k1];
            h2 n1i = Ub.a * Si[k0] + Ub.b * Sr[k0] + Ub.c * Si[k1] + Ub.d * Sr[k1];
            Sr[k0] = n0r; Si[k0] = n0i; Sr[k1] = n1r; Si[k1] = n1i;
        }
    }
    // ===== F2: ctrl q1 (k bit2), tgt q2 (k bit1) =====
    {
        const H2x4 Aa = ld4(&hsh[72]), Ab = ld4(&hsh[76]);
        const H2x4 Ba = ld4(&hsh[80]), Bb = ld4(&hsh[84]);
        u3_pair_h2(Sr[0], Si[0], Sr[2], Si[2], Aa.a, Aa.b, Aa.c, Aa.d, Ab.a, Ab.b, Ab.c, Ab.d);
        u3_pair_h2(Sr[1], Si[1], Sr[3], Si[3], Aa.a, Aa.b, Aa.c, Aa.d, Ab.a, Ab.b, Ab.c, Ab.d);
        u3_pair_h2(Sr[4], Si[4], Sr[6], Si[6], Ba.a, Ba.b, Ba.c, Ba.d, Bb.a, Bb.b, Bb.c, Bb.d);
        u3_pair_h2(Sr[5], Si[5], Sr[7], Si[7], Ba.a, Ba.b, Ba.c, Ba.d, Bb.a, Bb.b, Bb.c, Bb.d);
    }
    // ===== F3: ctrl q2 (k bit1), tgt q3 (k bit0) =====
    {
        const H2x4 Aa = ld4(&hsh[88]), Ab = ld4(&hsh[92]);
        const H2x4 Ba = ld4(&hsh[96]), Bb = ld4(&hsh[100]);
        u3_pair_h2(Sr[0], Si[0], Sr[1], Si[1], Aa.a, Aa.b, Aa.c, Aa.d, Ab.a, Ab.b, Ab.c, Ab.d);
        u3_pair_h2(Sr[4], Si[4], Sr[5], Si[5], Aa.a, Aa.b, Aa.c, Aa.d, Ab.a, Ab.b, Ab.c, Ab.d);
        u3_pair_h2(Sr[2], Si[2], Sr[3], Si[3], Ba.a, Ba.b, Ba.c, Ba.d, Bb.a, Bb.b, Bb.c, Bb.d);
        u3_pair_h2(Sr[6], Si[6], Sr[7], Si[7], Ba.a, Ba.b, Ba.c, Ba.d, Bb.a, Bb.b, Bb.c, Bb.d);
    }
    // ===== F4: ctrl q3 (k bit0), tgt q4 (lane bit5) =====
    {
        const int hi = (lane >> 5) & 1;
        const H2x4 RA = ld4(&hsh[104 + hi * 8]);   // eAr,eAi,fAr,fAi
        const H2x4 RB = ld4(&hsh[108 + hi * 8]);   // eBr,eBi,fBr,fBi
#pragma unroll
        for (int k = 0; k < 8; ++k) {
            const h2 er = (k & 1) ? RB.a : RA.a, ei = (k & 1) ? RB.b : RA.b;
            const h2 fr = (k & 1) ? RB.c : RA.c, fi = (k & 1) ? RB.d : RA.d;
            const HPair R = blkswap_h<5>(Sr[k], lane);
            const HPair I = blkswap_h<5>(Si[k], lane);
            Sr[k] = er * R.v0 - ei * I.v0 + fr * R.v1 - fi * I.v1;
            Si[k] = er * I.v0 + ei * R.v0 + fr * I.v1 + fi * R.v1;
        }
    }
    // ===== F5: ctrl bit5, tgt bit4 =====
    {
        const int idx = (((lane >> 5) & 1) << 1) | ((lane >> 4) & 1);
        const H2x4 M = ld4(&hsh[120 + idx * 4]);
        gate_blk_full_h2<4>(Sr, Si, lane, M.a, M.b, M.c, M.d);
    }
    // ===== F6..F9 =====
    {
        const int idx = (((lane >> 4) & 1) << 1) | ((lane >> 3) & 1);
        const H2x4 M = ld4(&hsh[136 + idx * 4]);
        gate_dpp_full_h2<3>(Sr, Si, M.a, M.b, M.c, M.d);
    }
    {
        const int idx = (((lane >> 3) & 1) << 1) | ((lane >> 2) & 1);
        const H2x4 M = ld4(&hsh[152 + idx * 4]);
        gate_dpp_full_h2<2>(Sr, Si, M.a, M.b, M.c, M.d);
    }
    {
        const int idx = (((lane >> 2) & 1) << 1) | ((lane >> 1) & 1);
        const H2x4 M = ld4(&hsh[168 + idx * 4]);
        gate_dpp_full_h2<1>(Sr, Si, M.a, M.b, M.c, M.d);
    }
    {
        const int idx = (((lane >> 1) & 1) << 1) | (lane & 1);
        const H2x4 M = ld4(&hsh[184 + idx * 4]);
        gate_dpp_full_h2<0>(Sr, Si, M.a, M.b, M.c, M.d);
    }
    // ===== CRY_1(9): ctrl q9 (lane bit0), tgt q0 (comp) =====
    {
        const int ctrl = lane & 1;
        const H2x2 C = ld2(&hsh[10 + ctrl * 2]);   // C2, S2={-sl,sl}
#pragma unroll
        for (int k = 0; k < 8; ++k) {
            const h2 Ar = Sr[k], Ai = Si[k];
            Sr[k] = C.a * Ar + C.b * Ar.yx;
            Si[k] = C.a * Ai + C.b * Ai.yx;
        }
    }

    // ===== measurement (fp32 accumulate) =====
    float ptot = 0.0f, z0p = 0.0f, z1p = 0.0f, z2p = 0.0f, z3p = 0.0f;
#pragma unroll
    for (int k = 0; k < 8; ++k) {
        float sk, dk;
#ifdef HAVE_FDOT2
        sk = __builtin_amdgcn_fdot2(Si[k], Si[k],
             __builtin_amdgcn_fdot2(Sr[k], Sr[k], 0.0f, false), false);
        h2 nr = Sr[k]; nr.y = -nr.y;
        h2 ni = Si[k]; ni.y = -ni.y;
        dk = __builtin_amdgcn_fdot2(Si[k], ni,
             __builtin_amdgcn_fdot2(Sr[k], nr, 0.0f, false), false);
#else
        const float arx = (float)Sr[k].x, ary = (float)Sr[k].y;
        const float aix = (float)Si[k].x, aiy = (float)Si[k].y;
        const float px = arx * arx + aix * aix;
        const float py = ary * ary + aiy * aiy;
        sk = px + py;
        dk = px - py;
#endif
        ptot += sk;
        z0p += dk;
        z1p += ((k >> 2) & 1) ? -sk : sk;
        z2p += ((k >> 1) & 1) ? -sk : sk;
        z3p += (k & 1) ? -sk : sk;
    }
    float d0, d1, d2, d3, d4, d5;
    {
        float a = ptot, p;
        p = partner1<0>(a); d0 = a - p; a += p;
        p = partner1<1>(a); d1 = a - p; a += p;
        p = partner1<2>(a); d2 = a - p; a += p;
        p = partner1<3>(a); d3 = a - p; a += p;
        { const FPair o = blkswap1<4>(a, lane); d4 = o.v0 - o.v1; a = o.v0 + o.v1; }
        { const FPair o = blkswap1<5>(a, lane); d5 = o.v0 - o.v1; }
    }
    const v2f z01 = vplus_reduce((v2f){z0p, z1p}, lane);
    const v2f z23 = vplus_reduce((v2f){z2p, z3p}, lane);
    float z[NQ];
    z[0] = z01.x; z[1] = z01.y; z[2] = z23.x; z[3] = z23.y;
    z[4] = d5;
    z[5] = plus_reduce<5>(d4, lane);
    z[6] = plus_reduce<4>(d3, lane);
    z[7] = plus_reduce<3>(d2, lane);
    z[8] = plus_reduce<2>(d1, lane);
    z[9] = plus_reduce<1>(d0, lane);

    if (lane == 0) {
#pragma unroll
        for (int q = 0; q < NQ; ++q) out[b * NQ + q] = z[q];
    }
}

extern "C" void kernel_launch(void* const* d_in, const int* in_sizes, int n_in,
                              void* d_out, int out_size, void* d_ws, size_t ws_size,
                              hipStream_t stream) {
    const float* inputs  = (const float*)d_in[0];
    const float* weights = (const float*)d_in[1];
    float* out = (float*)d_out;
    const int B = in_sizes[0] / NQ;

    qsim<<<(B + 3) / 4, 256, 0, stream>>>(inputs, weights, out, B);
}